// Round 14
// baseline (530.594 us; speedup 1.0000x reference)
//
#include <hip/hip_runtime.h>
#include <math.h>

// W=2, QN=64, H=28, HKV=4 (G=7), D=128, HID=3584; frags 8192/4096/2048 (Ktot=14336)
// R14: attention de-staged. K/V MFMA fragments read DIRECTLY from global
// (K fp32 -> per-lane convert; V from f16 Vt cache) -> zero per-tile barriers,
// zero K/V LDS. R13 showed 90%+ stall from the stage->drain->compute lockstep
// on L2-resident data (guide common-mistake #7). LDS = 38KB union (RQ/epilogue).
// gemm: R13 split-f16 MFMA 3-pass (proven). attn fallback (vt16==0): scalar gather.

typedef _Float16 f16;
typedef _Float16 h2 __attribute__((ext_vector_type(2)));
typedef _Float16 h4 __attribute__((ext_vector_type(4)));
typedef _Float16 h8 __attribute__((ext_vector_type(8)));
typedef float f32x16 __attribute__((ext_vector_type(16)));

static __device__ __forceinline__ float4 ld4(const float* p){ return *reinterpret_cast<const float4*>(p); }
static __device__ __forceinline__ void st4(float* p, const float4 v){ *reinterpret_cast<float4*>(p) = v; }
static __device__ __forceinline__ h2 pk(float a, float b){
  return __builtin_bit_cast(h2, __builtin_amdgcn_cvt_pkrtz(a, b));
}
static __device__ __forceinline__ h2 sw32(h2 v){
  int i = __builtin_bit_cast(int, v);
  i = __shfl_xor(i, 32, 64);
  return __builtin_bit_cast(h2, i);
}
static __device__ __forceinline__ h8 mk8(h2 a, h2 b, h2 c, h2 d){
  h8 r; r[0]=a[0]; r[1]=a[1]; r[2]=b[0]; r[3]=b[1]; r[4]=c[0]; r[5]=c[1]; r[6]=d[0]; r[7]=d[1]; return r;
}
static __device__ __forceinline__ h4 mk4(h2 a, h2 b){
  h4 r; r[0]=a[0]; r[1]=a[1]; r[2]=b[0]; r[3]=b[1]; return r;
}
static __device__ __forceinline__ h8 ld8h(const f16* p){
  const h4 a = *(const h4*)p;
  const h4 b = *(const h4*)(p + 4);
  h8 r; r[0]=a[0]; r[1]=a[1]; r[2]=a[2]; r[3]=a[3]; r[4]=b[0]; r[5]=b[1]; r[6]=b[2]; r[7]=b[3];
  return r;
}

#define SCALE 0.08838834764831845f

// ---------------- MFMA GEMM, split-f16 3-pass (fp32-accurate, R13 proven) ----------------
__global__ __launch_bounds__(256) void gemm_mfma_kernel(
    const float* __restrict__ A, const float* __restrict__ Bw,
    const float* __restrict__ bias, float* __restrict__ out, const int qlayout,
    float* __restrict__ Gpart, const int KS)
{
  __shared__ __align__(16) f16 Ah[128][68];
  __shared__ __align__(16) f16 Al[128][68];
  __shared__ __align__(16) f16 Bh[64][68];
  __shared__ __align__(16) f16 Bl[64][68];

  const int t = threadIdx.x;
  const int lane = t & 63;
  const int wv = t >> 6;
  const int l31 = lane & 31;
  const int hh = lane >> 5;
  const int nblk = blockIdx.x * 64;
  const int ks = blockIdx.y;
  const int kspan = 3584 / KS;
  const int kbeg = ks * kspan;

  f32x16 acc0, acc1;
#pragma unroll
  for (int g = 0; g < 16; ++g) { acc0[g] = 0.f; acc1[g] = 0.f; }

  for (int kc = kbeg; kc < kbeg + kspan; kc += 64) {
#pragma unroll
    for (int r = 0; r < 4; ++r) {
      const int li = r * 256 + t;
      const int m = li >> 3;
      const int k8 = (li & 7) * 8;
      const float* p = A + (size_t)m * 3584 + kc + k8;
      const float4 x0 = ld4(p), x1 = ld4(p + 4);
      const h2 a01 = pk(x0.x, x0.y), a23 = pk(x0.z, x0.w);
      const h2 a45 = pk(x1.x, x1.y), a67 = pk(x1.z, x1.w);
      const h2 r01 = pk(x0.x - (float)a01[0], x0.y - (float)a01[1]);
      const h2 r23 = pk(x0.z - (float)a23[0], x0.w - (float)a23[1]);
      const h2 r45 = pk(x1.x - (float)a45[0], x1.y - (float)a45[1]);
      const h2 r67 = pk(x1.z - (float)a67[0], x1.w - (float)a67[1]);
      *(h4*)&Ah[m][k8]     = mk4(a01, a23);
      *(h4*)&Ah[m][k8 + 4] = mk4(a45, a67);
      *(h4*)&Al[m][k8]     = mk4(r01, r23);
      *(h4*)&Al[m][k8 + 4] = mk4(r45, r67);
    }
#pragma unroll
    for (int r = 0; r < 2; ++r) {
      const int li = r * 256 + t;
      const int n = li >> 3;
      const int k8 = (li & 7) * 8;
      const float* p = Bw + (size_t)(nblk + n) * 3584 + kc + k8;
      const float4 x0 = ld4(p), x1 = ld4(p + 4);
      const h2 a01 = pk(x0.x, x0.y), a23 = pk(x0.z, x0.w);
      const h2 a45 = pk(x1.x, x1.y), a67 = pk(x1.z, x1.w);
      const h2 r01 = pk(x0.x - (float)a01[0], x0.y - (float)a01[1]);
      const h2 r23 = pk(x0.z - (float)a23[0], x0.w - (float)a23[1]);
      const h2 r45 = pk(x1.x - (float)a45[0], x1.y - (float)a45[1]);
      const h2 r67 = pk(x1.z - (float)a67[0], x1.w - (float)a67[1]);
      *(h4*)&Bh[n][k8]     = mk4(a01, a23);
      *(h4*)&Bh[n][k8 + 4] = mk4(a45, a67);
      *(h4*)&Bl[n][k8]     = mk4(r01, r23);
      *(h4*)&Bl[n][k8 + 4] = mk4(r45, r67);
    }
    __syncthreads();

#pragma unroll 2
    for (int k16 = 0; k16 < 4; ++k16) {
      const int ko = k16 * 16 + hh * 8;
      const h8 ah  = ld8h(&Ah[wv * 32 + l31][ko]);
      const h8 al  = ld8h(&Al[wv * 32 + l31][ko]);
      const h8 bh0 = ld8h(&Bh[l31][ko]);
      const h8 bl0 = ld8h(&Bl[l31][ko]);
      const h8 bh1 = ld8h(&Bh[32 + l31][ko]);
      const h8 bl1 = ld8h(&Bl[32 + l31][ko]);
      acc0 = __builtin_amdgcn_mfma_f32_32x32x16_f16(ah, bh0, acc0, 0, 0, 0);
      acc0 = __builtin_amdgcn_mfma_f32_32x32x16_f16(ah, bl0, acc0, 0, 0, 0);
      acc0 = __builtin_amdgcn_mfma_f32_32x32x16_f16(al, bh0, acc0, 0, 0, 0);
      acc1 = __builtin_amdgcn_mfma_f32_32x32x16_f16(ah, bh1, acc1, 0, 0, 0);
      acc1 = __builtin_amdgcn_mfma_f32_32x32x16_f16(ah, bl1, acc1, 0, 0, 0);
      acc1 = __builtin_amdgcn_mfma_f32_32x32x16_f16(al, bh1, acc1, 0, 0, 0);
    }
    __syncthreads();
  }

  if (Gpart) {
    float* gp = Gpart + (size_t)ks * 458752;
#pragma unroll
    for (int reg = 0; reg < 16; ++reg) {
      const int m = wv * 32 + (reg & 3) + 8 * (reg >> 2) + 4 * hh;
      gp[(size_t)m * 3584 + nblk + l31]      = acc0[reg];
      gp[(size_t)m * 3584 + nblk + 32 + l31] = acc1[reg];
    }
    return;
  }
#pragma unroll
  for (int reg = 0; reg < 16; ++reg) {
    const int m = wv * 32 + (reg & 3) + 8 * (reg >> 2) + 4 * hh;
#pragma unroll
    for (int nt = 0; nt < 2; ++nt) {
      const int n = nblk + nt * 32 + l31;
      float v = (nt ? acc1[reg] : acc0[reg]) + (bias ? bias[n] : 0.f);
      if (qlayout) {
        const int w = m >> 6, qn = m & 63, hcol = n >> 7, d = n & 127;
        out[(((size_t)(w * 28 + hcol)) * 64 + qn) * 128 + d] = v;
      } else {
        out[(size_t)m * 3584 + n] = v;
      }
    }
  }
}

// reduce KS partials, add bias, apply layout. grid 448 x 256 (one float4 each).
__global__ __launch_bounds__(256) void gemm_reduce_kernel(
    const float* __restrict__ Gpart, const float* __restrict__ bias,
    float* __restrict__ out, const int KS, const int qlayout)
{
  const int idx = blockIdx.x * 256 + threadIdx.x;
  const int m = idx / 896;
  const int n = (idx - m * 896) * 4;
  float4 a = ld4(Gpart + (size_t)m * 3584 + n);
  for (int ss = 1; ss < KS; ++ss) {
    const float4 b = ld4(Gpart + (size_t)ss * 458752 + (size_t)m * 3584 + n);
    a.x += b.x; a.y += b.y; a.z += b.z; a.w += b.w;
  }
  if (bias) { a.x += bias[n]; a.y += bias[n + 1]; a.z += bias[n + 2]; a.w += bias[n + 3]; }
  if (qlayout) {
    const int w = m >> 6, qn = m & 63, hh = n >> 7, d = n & 127;
    st4(out + (((size_t)(w * 28 + hh)) * 64 + qn) * 128 + d, a);
  } else {
    st4(out + (size_t)m * 3584 + n, a);
  }
}

// ---------------- pre-pass: V -> f16 transposed [kvh][128][14336] ----------------
__global__ __launch_bounds__(256) void vtrans_kernel(
    const float* __restrict__ V0, const float* __restrict__ V1, const float* __restrict__ V2,
    f16* __restrict__ Vt)
{
  __shared__ __align__(16) f16 T[64 * 136];
  const int bid = blockIdx.x;
  const int kvh = bid / 224;
  const int g0 = (bid % 224) * 64;
  const int t = threadIdx.x;
#pragma unroll
  for (int rep = 0; rep < 8; ++rep) {
    const int li = rep * 256 + t;
    const int k = li >> 5;
    const int d0 = (li & 31) * 4;
    const int g = g0 + k;
    const float* src;
    if (g < 8192)       src = V0 + ((size_t)kvh * 8192 + g) * 128 + d0;
    else if (g < 12288) src = V1 + ((size_t)kvh * 4096 + (g - 8192)) * 128 + d0;
    else                src = V2 + ((size_t)kvh * 2048 + (g - 12288)) * 128 + d0;
    const float4 v = ld4(src);
    h2 x = pk(v.x, v.y), y = pk(v.z, v.w);
    h4 q4; q4[0] = x[0]; q4[1] = x[1]; q4[2] = y[0]; q4[3] = y[1];
    *(h4*)((char*)T + k * 272 + d0 * 2) = q4;
  }
  __syncthreads();
#pragma unroll
  for (int rep = 0; rep < 4; ++rep) {
    const int li = rep * 256 + t;
    const int d = li >> 3;
    const int kc = (li & 7) * 8;
    h8 o;
#pragma unroll
    for (int j = 0; j < 8; ++j) o[j] = T[(kc + j) * 136 + d];
    *(h8*)(Vt + ((size_t)kvh * 128 + d) * 14336 + g0 + kc) = o;
  }
}

// ---------------- barrier-free MFMA flash attention (direct fragments) ----------------
// 8 waves (512 thr): group g=wv>>2 owns q-half g, wave wv&3 owns keys [wk,wk+32).
// K fragments: direct fp32 global loads + in-register f16 convert.
// V fragments: direct h8 loads from f16 Vt cache. NO per-tile barriers/LDS tiles.
// LDS: union{ RQ 16KB (loop) | epilogue 38KB }.
__global__ __launch_bounds__(512, 4) void attn_mfma_kernel(
    const float* __restrict__ q_ws,
    const float* __restrict__ cosT, const float* __restrict__ sinT,
    const float* __restrict__ K0, const float* __restrict__ K1, const float* __restrict__ K2,
    const float* __restrict__ V0, const float* __restrict__ V1, const float* __restrict__ V2,
    const int* __restrict__ loc,
    const f16* __restrict__ Vt, const int vt16,
    float* __restrict__ attn,
    float* __restrict__ Opart, float* __restrict__ Ml, const int NS)
{
  union ShmU {
    f16 rq[64 * 128];                                   // 16 KB, alive in main loop
    struct { float o[2][32 * 132]; float m[8][32]; float l[8][32];
             float lg[2][32]; float mg[2][32]; } e;     // ~38 KB, epilogue only
  };
  __shared__ __align__(16) ShmU S;

  int unit, s, h, w, kvh;
  if (NS > 1) {
    const int C = 4 * NS;
    const int combo = blockIdx.x % C;
    const int idx = blockIdx.x / C;
    kvh = combo / NS; s = combo % NS;
    const int hh7 = idx % 7;
    w = idx / 7;
    h = kvh * 7 + hh7;
    unit = w * 28 + h;
  } else {
    unit = blockIdx.x; s = 0;
    h = unit % 28; w = unit / 28; kvh = h / 7;
  }

  const int tiles_per = 112 / NS;
  const int tile0 = s * tiles_per;
  const int tile1 = tile0 + tiles_per;

  const int t = threadIdx.x;
  const int lane = t & 63;
  const int wv = t >> 6;
  const int g  = wv >> 2;
  const int wg = wv & 3;
  const int wk = wg * 32;
  const int l31 = lane & 31;
  const int hh = lane >> 5;

  const size_t qb = (size_t)unit * 64 * 128;

  const float* K0b = K0 + (size_t)kvh * 8192 * 128;
  const float* K1b = K1 + (size_t)kvh * 4096 * 128;
  const float* K2b = K2 + (size_t)kvh * 2048 * 128;
  const float* V0b = V0 + (size_t)kvh * 8192 * 128;
  const float* V1b = V1 + (size_t)kvh * 4096 * 128;
  const float* V2b = V2 + (size_t)kvh * 2048 * 128;
  const f16* Vtg = Vt ? (Vt + (size_t)kvh * 128 * 14336) : (const f16*)nullptr;

  f32x16 acc[4];
#pragma unroll
  for (int i = 0; i < 4; ++i)
#pragma unroll
    for (int gg = 0; gg < 16; ++gg) acc[i][gg] = 0.f;

  h8 rq[8];
  float m_run = -INFINITY, l_run = 0.f;
  int locq = 0;
  int fprev = -1;

  for (int tile = tile0; tile < tile1; ++tile) {
    int f, rel; const float *Kg, *Vg;
    if (tile < 64)      { f = 0; rel = tile * 128;        Kg = K0b; Vg = V0b; }
    else if (tile < 96) { f = 1; rel = (tile - 64) * 128; Kg = K1b; Vg = V1b; }
    else                { f = 2; rel = (tile - 96) * 128; Kg = K2b; Vg = V2b; }
    const int gcat = tile * 128;
    const bool fsw = (f != fprev);
    fprev = f;

    if (fsw) {
      __syncthreads();               // all waves done reading previous RQ
      const size_t cb = ((size_t)(f * 2 + w)) * 64 * 128;
#pragma unroll
      for (int rep = 0; rep < 2; ++rep) {
        const int qr = rep * 32 + (t >> 4);
        const int d0 = (t & 15) * 8;
        const float* qp = q_ws + qb + (size_t)qr * 128;
        const float4 a0 = ld4(qp + d0), a1 = ld4(qp + d0 + 4);
        const int pd = (d0 < 64) ? d0 + 64 : d0 - 64;
        const float4 r0 = ld4(qp + pd), r1 = ld4(qp + pd + 4);
        const float sg = (d0 < 64) ? -1.f : 1.f;
        const float* cp = cosT + cb + (size_t)qr * 128;
        const float* sp = sinT + cb + (size_t)qr * 128;
        const float4 c0 = ld4(cp + d0), c1 = ld4(cp + d0 + 4);
        const float4 s0 = ld4(sp + d0), s1 = ld4(sp + d0 + 4);
        h8 hv = mk8(pk(a0.x * c0.x + sg * r0.x * s0.x, a0.y * c0.y + sg * r0.y * s0.y),
                    pk(a0.z * c0.z + sg * r0.z * s0.z, a0.w * c0.w + sg * r0.w * s0.w),
                    pk(a1.x * c1.x + sg * r1.x * s1.x, a1.y * c1.y + sg * r1.y * s1.y),
                    pk(a1.z * c1.z + sg * r1.z * s1.z, a1.w * c1.w + sg * r1.w * s1.w));
        *(h8*)((char*)S.rq + qr * 256 + ((d0 * 2) ^ ((qr & 7) << 4))) = hv;
      }
      locq = loc[(f * 2 + w) * 64 + g * 32 + l31];
      __syncthreads();
#pragma unroll
      for (int c = 0; c < 8; ++c)
        rq[c] = *(const h8*)((const char*)S.rq + (g * 32 + l31) * 256 +
                             (((c * 32) + hh * 16) ^ ((l31 & 7) << 4)));
    }

    // ---- QK^T: K fragments direct from global fp32 (convert in-register) ----
    f32x16 sacc;
#pragma unroll
    for (int gg = 0; gg < 16; ++gg) sacc[gg] = 0.f;
    {
      const float* kp = Kg + (size_t)(rel + wk + l31) * 128 + hh * 8;
      __builtin_amdgcn_s_setprio(1);
#pragma unroll 2
      for (int c = 0; c < 8; ++c) {
        const float4 x0 = ld4(kp + c * 16);
        const float4 x1 = ld4(kp + c * 16 + 4);
        const h8 a = mk8(pk(x0.x, x0.y), pk(x0.z, x0.w), pk(x1.x, x1.y), pk(x1.z, x1.w));
        sacc = __builtin_amdgcn_mfma_f32_32x32x16_f16(a, rq[c], sacc, 0, 0, 0);
      }
      __builtin_amdgcn_s_setprio(0);
    }

    // ---- mask + scale + online softmax ----
    float p[16];
    float mt = -INFINITY;
#pragma unroll
    for (int gg = 0; gg < 16; ++gg) {
      const int kl = (gg & 3) + 8 * (gg >> 2) + 4 * hh;
      float z = sacc[gg] * SCALE;
      if (rel + wk + kl > locq) z = -INFINITY;
      p[gg] = z;
      mt = fmaxf(mt, z);
    }
    mt = fmaxf(mt, __shfl_xor(mt, 32, 64));
    if (!__all(mt <= m_run + 8.f)) {        // defer-max (T13)
      const float mn = fmaxf(m_run, mt);
      const float rr = __expf(m_run - mn);
      l_run *= rr;
#pragma unroll
      for (int i = 0; i < 4; ++i)
#pragma unroll
        for (int gg = 0; gg < 16; ++gg) acc[i][gg] *= rr;
      m_run = mn;
    }
    float ls = 0.f;
#pragma unroll
    for (int gg = 0; gg < 16; ++gg) { const float pe = __expf(p[gg] - m_run); p[gg] = pe; ls += pe; }
    l_run += ls + __shfl_xor(ls, 32, 64);

    // ---- P -> f16 B-fragments ----
    h2 wvv[8], xvv[8];
#pragma unroll
    for (int gg = 0; gg < 8; ++gg) wvv[gg] = pk(p[2 * gg], p[2 * gg + 1]);
#pragma unroll
    for (int gg = 0; gg < 8; ++gg) xvv[gg] = sw32(wvv[gg]);
    const h8 bp0 = hh ? mk8(xvv[2], xvv[3], wvv[2], wvv[3]) : mk8(wvv[0], wvv[1], xvv[0], xvv[1]);
    const h8 bp1 = hh ? mk8(xvv[6], xvv[7], wvv[6], wvv[7]) : mk8(wvv[4], wvv[5], xvv[4], xvv[5]);

    // ---- PV: V^T fragments direct from f16 Vt cache ----
    __builtin_amdgcn_s_setprio(1);
    if (vt16) {
#pragma unroll 2
      for (int dt = 0; dt < 4; ++dt) {
        const f16* vp = Vtg + (size_t)(dt * 32 + l31) * 14336 + gcat + wk + hh * 8;
        const h8 a0 = *(const h8*)vp;
        const h8 a1 = *(const h8*)(vp + 16);
        acc[dt] = __builtin_amdgcn_mfma_f32_32x32x16_f16(a0, bp0, acc[dt], 0, 0, 0);
        acc[dt] = __builtin_amdgcn_mfma_f32_32x32x16_f16(a1, bp1, acc[dt], 0, 0, 0);
      }
    } else {
      // correctness fallback (never exercised with current ws): scalar gather
#pragma unroll
      for (int dt = 0; dt < 4; ++dt) {
        const int d = dt * 32 + l31;
        h8 a0, a1;
#pragma unroll
        for (int j = 0; j < 8; j += 2) {
          const float v0 = Vg[(size_t)(rel + wk + hh * 8 + j) * 128 + d];
          const float v1 = Vg[(size_t)(rel + wk + hh * 8 + j + 1) * 128 + d];
          const h2 x = pk(v0, v1); a0[j] = x[0]; a0[j + 1] = x[1];
          const float u0 = Vg[(size_t)(rel + wk + 16 + hh * 8 + j) * 128 + d];
          const float u1 = Vg[(size_t)(rel + wk + 16 + hh * 8 + j + 1) * 128 + d];
          const h2 y = pk(u0, u1); a1[j] = y[0]; a1[j + 1] = y[1];
        }
        acc[dt] = __builtin_amdgcn_mfma_f32_32x32x16_f16(a0, bp0, acc[dt], 0, 0, 0);
        acc[dt] = __builtin_amdgcn_mfma_f32_32x32x16_f16(a1, bp1, acc[dt], 0, 0, 0);
      }
    }
    __builtin_amdgcn_s_setprio(0);
  }

  // ---- epilogue: per-group cross-wave combine (RQ dead; union with S.e safe:
  // last fsw's closing barrier guarantees no further RQ reads) ----
  __syncthreads();
  if (lane < 32) { S.e.m[wv][l31] = m_run; S.e.l[wv][l31] = l_run; }
  {
    const float4 z4 = make_float4(0.f, 0.f, 0.f, 0.f);
    for (int i = t; i < 2 * 32 * 132 / 4; i += 512) ((float4*)S.e.o)[i] = z4;
  }
  __syncthreads();
  float M = -INFINITY;
#pragma unroll
  for (int j = 0; j < 4; ++j) M = fmaxf(M, S.e.m[g * 4 + j][l31]);
  float Lg = 0.f;
#pragma unroll
  for (int j = 0; j < 4; ++j) Lg += S.e.l[g * 4 + j][l31] * __expf(S.e.m[g * 4 + j][l31] - M);
  const float swf = __expf(m_run - M);
  if (wg == 0 && lane < 32) { S.e.lg[g][l31] = Lg; S.e.mg[g][l31] = M; }
  __syncthreads();

#pragma unroll
  for (int r = 0; r < 4; ++r) {
#pragma unroll
    for (int dt = 0; dt < 4; ++dt) {
#pragma unroll
      for (int gq = 0; gq < 4; ++gq) {
        if ((((dt * 2 + (gq >> 1)) - wg - r) & 3) == 0) {   // wave-uniform predicate
          const int db = dt * 32 + 8 * gq + 4 * hh;
          float4* pp = (float4*)&S.e.o[g][l31 * 132 + db];
          float4 v = *pp;
          v.x += acc[dt][gq * 4 + 0] * swf;
          v.y += acc[dt][gq * 4 + 1] * swf;
          v.z += acc[dt][gq * 4 + 2] * swf;
          v.w += acc[dt][gq * 4 + 3] * swf;
          *pp = v;
        }
      }
    }
    __syncthreads();
  }

  {
    const int q = t >> 3;
    const int hf = q >> 5;
    const int qr = q & 31;
    const int d0 = (t & 7) * 16;
    const float* op = &S.e.o[hf][qr * 132 + d0];
    if (NS == 1) {
      const float invl = 1.f / S.e.lg[hf][qr];
      float* dst = attn + ((size_t)(w * 64 + q)) * 3584 + h * 128 + d0;
#pragma unroll
      for (int i = 0; i < 4; ++i)
        st4(dst + 4 * i, make_float4(op[4*i] * invl, op[4*i+1] * invl, op[4*i+2] * invl, op[4*i+3] * invl));
    } else {
      float* dst = Opart + (((size_t)unit * NS + s) * 64 + q) * 128 + d0;
#pragma unroll
      for (int i = 0; i < 4; ++i)
        st4(dst + 4 * i, make_float4(op[4*i], op[4*i+1], op[4*i+2], op[4*i+3]));
      if (t < 64) {
        float* mlp = Ml + ((size_t)unit * NS + s) * 128;
        mlp[t] = S.e.mg[t >> 5][t & 31];
        mlp[64 + t] = S.e.lg[t >> 5][t & 31];
      }
    }
  }
}

// merge NS split partials. grid 56 x 512.
__global__ __launch_bounds__(512) void attn_combine_kernel(
    const float* __restrict__ Opart, const float* __restrict__ Ml,
    float* __restrict__ attn, const int NS)
{
  const int unit = blockIdx.x;
  const int h = unit % 28;
  const int w = unit / 28;
  const int t = threadIdx.x;
  const int q = t >> 3;
  const int d0 = (t & 7) * 16;

  float M = -INFINITY;
  for (int s = 0; s < NS; ++s) M = fmaxf(M, Ml[((size_t)unit * NS + s) * 128 + q]);
  float L = 0.f;
  float acc[16];
#pragma unroll
  for (int i = 0; i < 16; ++i) acc[i] = 0.f;
  for (int s = 0; s < NS; ++s) {
    const float ms = Ml[((size_t)unit * NS + s) * 128 + q];
    const float ls = Ml[((size_t)unit * NS + s) * 128 + 64 + q];
    const float wgt = __expf(ms - M);
    L += ls * wgt;
    const float* op = Opart + (((size_t)unit * NS + s) * 64 + q) * 128 + d0;
#pragma unroll
    for (int i = 0; i < 4; ++i) {
      const float4 v = ld4(op + 4 * i);
      acc[4 * i + 0] += v.x * wgt;
      acc[4 * i + 1] += v.y * wgt;
      acc[4 * i + 2] += v.z * wgt;
      acc[4 * i + 3] += v.w * wgt;
    }
  }
  const float invl = 1.f / L;
  float* dst = attn + ((size_t)(w * 64 + q)) * 3584 + h * 128 + d0;
#pragma unroll
  for (int i = 0; i < 4; ++i) {
    const float4 o = make_float4(acc[4 * i + 0] * invl, acc[4 * i + 1] * invl,
                                 acc[4 * i + 2] * invl, acc[4 * i + 3] * invl);
    st4(dst + 4 * i, o);
  }
}

extern "C" void kernel_launch(void* const* d_in, const int* in_sizes, int n_in,
                              void* d_out, int out_size, void* d_ws, size_t ws_size,
                              hipStream_t stream) {
  (void)n_in; (void)out_size;
  const float* hs = (const float*)d_in[0];
  const float* wq = (const float*)d_in[1];
  const float* bq = (const float*)d_in[2];
  const float* wo = (const float*)d_in[3];

  const float *K0, *V0, *K1, *V1, *K2, *V2, *cosT, *sinT;
  const int* loc;
  if (in_sizes[5] == in_sizes[4]) {  // dict order
    K0 = (const float*)d_in[4]; V0 = (const float*)d_in[5];
    K1 = (const float*)d_in[6]; V1 = (const float*)d_in[7];
    K2 = (const float*)d_in[8]; V2 = (const float*)d_in[9];
    loc = (const int*)d_in[10];
    cosT = (const float*)d_in[11]; sinT = (const float*)d_in[12];
  } else {                            // signature order
    K0 = (const float*)d_in[4]; K1 = (const float*)d_in[5]; K2 = (const float*)d_in[6];
    V0 = (const float*)d_in[7]; V1 = (const float*)d_in[8]; V2 = (const float*)d_in[9];
    cosT = (const float*)d_in[10]; sinT = (const float*)d_in[11];
    loc = (const int*)d_in[12];
  }

  float* outp = (float*)d_out;          // q [w][h][qn][d] between gemm1 and attn
  float* attn = (float*)d_ws;           // [128][3584] = 1,835,008 B
  char* base = (char*)d_ws;

  const size_t ATTN_B = (size_t)458752 * 4;            // 1,835,008
  const size_t RB = (size_t)4 * 128 * 14336 * 2;       // 14,680,064: Vt f16 / Gpart KS=8
  auto opartBytes = [](int ns){ return (size_t)56 * ns * 33280; };

  size_t off = ATTN_B;
  f16* Vt = nullptr; int vt16 = 0;
  float *Opart = nullptr, *Ml = nullptr, *Gpart = nullptr;
  int NS = 1, KS = 1;

  // Region R: Vt (attn phase) / Gpart (gemm phases) — lifetimes disjoint.
  const bool haveR = (ws_size >= off + RB + opartBytes(2));
  if (haveR) {
    Vt = (f16*)(base + off); vt16 = 1;
    Gpart = (float*)(base + off); KS = 8;           // 8 x 1.835 MB = RB exactly
    off += RB;
  }
  for (int cand = 8; cand >= 2; cand >>= 1) {
    if (ws_size >= off + opartBytes(cand)) {
      NS = cand;
      Opart = (float*)(base + off);
      Ml = Opart + (size_t)56 * cand * 64 * 128;
      off += opartBytes(cand);
      break;
    }
  }
  if (!haveR) {
    if (ws_size >= off + (size_t)8 * ATTN_B)      { KS = 8; Gpart = (float*)(base + off); }
    else if (ws_size >= off + (size_t)4 * ATTN_B) { KS = 4; Gpart = (float*)(base + off); }
  }

  // ---- gemm1: q = hs @ wq^T + bq, q-layout (grid x = 3584/64 = 56) ----
  if (KS > 1) {
    gemm_mfma_kernel<<<dim3(56, KS, 1), 256, 0, stream>>>(hs, wq, nullptr, nullptr, 1, Gpart, KS);
    gemm_reduce_kernel<<<448, 256, 0, stream>>>(Gpart, bq, outp, KS, 1);
  } else {
    gemm_mfma_kernel<<<dim3(56, 1, 1), 256, 0, stream>>>(hs, wq, bq, outp, 1, nullptr, 1);
  }

  if (vt16) vtrans_kernel<<<896, 256, 0, stream>>>(V0, V1, V2, Vt);   // after reduce1

  // ---- attention (barrier-free direct fragments, split-K x NS) ----
  const int grid = (NS > 1) ? 56 * NS : 56;
  attn_mfma_kernel<<<grid, 512, 0, stream>>>(
      outp, cosT, sinT, K0, K1, K2, V0, V1, V2, loc, Vt, vt16, attn, Opart, Ml, NS);
  if (NS > 1) attn_combine_kernel<<<56, 512, 0, stream>>>(Opart, Ml, attn, NS);

  // ---- gemm2: out = attn @ wo^T (Gpart overwrites Vt — Vt dead after attn) ----
  if (KS > 1) {
    gemm_mfma_kernel<<<dim3(56, KS, 1), 256, 0, stream>>>(attn, wo, nullptr, nullptr, 0, Gpart, KS);
    gemm_reduce_kernel<<<448, 256, 0, stream>>>(Gpart, nullptr, outp, KS, 0);
  } else {
    gemm_mfma_kernel<<<dim3(56, 1, 1), 256, 0, stream>>>(attn, wo, nullptr, outp, 0, nullptr, 1);
  }
}

// Round 15
// 524.386 us; speedup vs baseline: 1.0118x; 1.0118x over previous
//
#include <hip/hip_runtime.h>
#include <math.h>

// W=2, QN=64, H=28, HKV=4 (G=7), D=128, HID=3584; frags 8192/4096/2048 (Ktot=14336)
// R15: R14's barrier-free design, rule-#20 bug fixed. R14 put `#pragma unroll 2`
// on loops indexing rq[c] and acc[dt] -> runtime indices -> 96 VGPRs of state
// demoted to scratch (VGPR=60, WRITE 952MB). Fix: FULL unroll on both loops so
// all array indices are compile-time. Everything else identical to R14.
// gemm: R13 split-f16 MFMA 3-pass (proven, 53us total).

typedef _Float16 f16;
typedef _Float16 h2 __attribute__((ext_vector_type(2)));
typedef _Float16 h4 __attribute__((ext_vector_type(4)));
typedef _Float16 h8 __attribute__((ext_vector_type(8)));
typedef float f32x16 __attribute__((ext_vector_type(16)));

static __device__ __forceinline__ float4 ld4(const float* p){ return *reinterpret_cast<const float4*>(p); }
static __device__ __forceinline__ void st4(float* p, const float4 v){ *reinterpret_cast<float4*>(p) = v; }
static __device__ __forceinline__ h2 pk(float a, float b){
  return __builtin_bit_cast(h2, __builtin_amdgcn_cvt_pkrtz(a, b));
}
static __device__ __forceinline__ h2 sw32(h2 v){
  int i = __builtin_bit_cast(int, v);
  i = __shfl_xor(i, 32, 64);
  return __builtin_bit_cast(h2, i);
}
static __device__ __forceinline__ h8 mk8(h2 a, h2 b, h2 c, h2 d){
  h8 r; r[0]=a[0]; r[1]=a[1]; r[2]=b[0]; r[3]=b[1]; r[4]=c[0]; r[5]=c[1]; r[6]=d[0]; r[7]=d[1]; return r;
}
static __device__ __forceinline__ h4 mk4(h2 a, h2 b){
  h4 r; r[0]=a[0]; r[1]=a[1]; r[2]=b[0]; r[3]=b[1]; return r;
}
static __device__ __forceinline__ h8 ld8h(const f16* p){
  const h4 a = *(const h4*)p;
  const h4 b = *(const h4*)(p + 4);
  h8 r; r[0]=a[0]; r[1]=a[1]; r[2]=a[2]; r[3]=a[3]; r[4]=b[0]; r[5]=b[1]; r[6]=b[2]; r[7]=b[3];
  return r;
}

#define SCALE 0.08838834764831845f

// ---------------- MFMA GEMM, split-f16 3-pass (fp32-accurate, R13 proven) ----------------
__global__ __launch_bounds__(256) void gemm_mfma_kernel(
    const float* __restrict__ A, const float* __restrict__ Bw,
    const float* __restrict__ bias, float* __restrict__ out, const int qlayout,
    float* __restrict__ Gpart, const int KS)
{
  __shared__ __align__(16) f16 Ah[128][68];
  __shared__ __align__(16) f16 Al[128][68];
  __shared__ __align__(16) f16 Bh[64][68];
  __shared__ __align__(16) f16 Bl[64][68];

  const int t = threadIdx.x;
  const int lane = t & 63;
  const int wv = t >> 6;
  const int l31 = lane & 31;
  const int hh = lane >> 5;
  const int nblk = blockIdx.x * 64;
  const int ks = blockIdx.y;
  const int kspan = 3584 / KS;
  const int kbeg = ks * kspan;

  f32x16 acc0, acc1;
#pragma unroll
  for (int g = 0; g < 16; ++g) { acc0[g] = 0.f; acc1[g] = 0.f; }

  for (int kc = kbeg; kc < kbeg + kspan; kc += 64) {
#pragma unroll
    for (int r = 0; r < 4; ++r) {
      const int li = r * 256 + t;
      const int m = li >> 3;
      const int k8 = (li & 7) * 8;
      const float* p = A + (size_t)m * 3584 + kc + k8;
      const float4 x0 = ld4(p), x1 = ld4(p + 4);
      const h2 a01 = pk(x0.x, x0.y), a23 = pk(x0.z, x0.w);
      const h2 a45 = pk(x1.x, x1.y), a67 = pk(x1.z, x1.w);
      const h2 r01 = pk(x0.x - (float)a01[0], x0.y - (float)a01[1]);
      const h2 r23 = pk(x0.z - (float)a23[0], x0.w - (float)a23[1]);
      const h2 r45 = pk(x1.x - (float)a45[0], x1.y - (float)a45[1]);
      const h2 r67 = pk(x1.z - (float)a67[0], x1.w - (float)a67[1]);
      *(h4*)&Ah[m][k8]     = mk4(a01, a23);
      *(h4*)&Ah[m][k8 + 4] = mk4(a45, a67);
      *(h4*)&Al[m][k8]     = mk4(r01, r23);
      *(h4*)&Al[m][k8 + 4] = mk4(r45, r67);
    }
#pragma unroll
    for (int r = 0; r < 2; ++r) {
      const int li = r * 256 + t;
      const int n = li >> 3;
      const int k8 = (li & 7) * 8;
      const float* p = Bw + (size_t)(nblk + n) * 3584 + kc + k8;
      const float4 x0 = ld4(p), x1 = ld4(p + 4);
      const h2 a01 = pk(x0.x, x0.y), a23 = pk(x0.z, x0.w);
      const h2 a45 = pk(x1.x, x1.y), a67 = pk(x1.z, x1.w);
      const h2 r01 = pk(x0.x - (float)a01[0], x0.y - (float)a01[1]);
      const h2 r23 = pk(x0.z - (float)a23[0], x0.w - (float)a23[1]);
      const h2 r45 = pk(x1.x - (float)a45[0], x1.y - (float)a45[1]);
      const h2 r67 = pk(x1.z - (float)a67[0], x1.w - (float)a67[1]);
      *(h4*)&Bh[n][k8]     = mk4(a01, a23);
      *(h4*)&Bh[n][k8 + 4] = mk4(a45, a67);
      *(h4*)&Bl[n][k8]     = mk4(r01, r23);
      *(h4*)&Bl[n][k8 + 4] = mk4(r45, r67);
    }
    __syncthreads();

#pragma unroll 2
    for (int k16 = 0; k16 < 4; ++k16) {
      const int ko = k16 * 16 + hh * 8;
      const h8 ah  = ld8h(&Ah[wv * 32 + l31][ko]);
      const h8 al  = ld8h(&Al[wv * 32 + l31][ko]);
      const h8 bh0 = ld8h(&Bh[l31][ko]);
      const h8 bl0 = ld8h(&Bl[l31][ko]);
      const h8 bh1 = ld8h(&Bh[32 + l31][ko]);
      const h8 bl1 = ld8h(&Bl[32 + l31][ko]);
      acc0 = __builtin_amdgcn_mfma_f32_32x32x16_f16(ah, bh0, acc0, 0, 0, 0);
      acc0 = __builtin_amdgcn_mfma_f32_32x32x16_f16(ah, bl0, acc0, 0, 0, 0);
      acc0 = __builtin_amdgcn_mfma_f32_32x32x16_f16(al, bh0, acc0, 0, 0, 0);
      acc1 = __builtin_amdgcn_mfma_f32_32x32x16_f16(ah, bh1, acc1, 0, 0, 0);
      acc1 = __builtin_amdgcn_mfma_f32_32x32x16_f16(ah, bl1, acc1, 0, 0, 0);
      acc1 = __builtin_amdgcn_mfma_f32_32x32x16_f16(al, bh1, acc1, 0, 0, 0);
    }
    __syncthreads();
  }

  if (Gpart) {
    float* gp = Gpart + (size_t)ks * 458752;
#pragma unroll
    for (int reg = 0; reg < 16; ++reg) {
      const int m = wv * 32 + (reg & 3) + 8 * (reg >> 2) + 4 * hh;
      gp[(size_t)m * 3584 + nblk + l31]      = acc0[reg];
      gp[(size_t)m * 3584 + nblk + 32 + l31] = acc1[reg];
    }
    return;
  }
#pragma unroll
  for (int reg = 0; reg < 16; ++reg) {
    const int m = wv * 32 + (reg & 3) + 8 * (reg >> 2) + 4 * hh;
#pragma unroll
    for (int nt = 0; nt < 2; ++nt) {
      const int n = nblk + nt * 32 + l31;
      float v = (nt ? acc1[reg] : acc0[reg]) + (bias ? bias[n] : 0.f);
      if (qlayout) {
        const int w = m >> 6, qn = m & 63, hcol = n >> 7, d = n & 127;
        out[(((size_t)(w * 28 + hcol)) * 64 + qn) * 128 + d] = v;
      } else {
        out[(size_t)m * 3584 + n] = v;
      }
    }
  }
}

// reduce KS partials, add bias, apply layout. grid 448 x 256 (one float4 each).
__global__ __launch_bounds__(256) void gemm_reduce_kernel(
    const float* __restrict__ Gpart, const float* __restrict__ bias,
    float* __restrict__ out, const int KS, const int qlayout)
{
  const int idx = blockIdx.x * 256 + threadIdx.x;
  const int m = idx / 896;
  const int n = (idx - m * 896) * 4;
  float4 a = ld4(Gpart + (size_t)m * 3584 + n);
  for (int ss = 1; ss < KS; ++ss) {
    const float4 b = ld4(Gpart + (size_t)ss * 458752 + (size_t)m * 3584 + n);
    a.x += b.x; a.y += b.y; a.z += b.z; a.w += b.w;
  }
  if (bias) { a.x += bias[n]; a.y += bias[n + 1]; a.z += bias[n + 2]; a.w += bias[n + 3]; }
  if (qlayout) {
    const int w = m >> 6, qn = m & 63, hh = n >> 7, d = n & 127;
    st4(out + (((size_t)(w * 28 + hh)) * 64 + qn) * 128 + d, a);
  } else {
    st4(out + (size_t)m * 3584 + n, a);
  }
}

// ---------------- pre-pass: V -> f16 transposed [kvh][128][14336] ----------------
__global__ __launch_bounds__(256) void vtrans_kernel(
    const float* __restrict__ V0, const float* __restrict__ V1, const float* __restrict__ V2,
    f16* __restrict__ Vt)
{
  __shared__ __align__(16) f16 T[64 * 136];
  const int bid = blockIdx.x;
  const int kvh = bid / 224;
  const int g0 = (bid % 224) * 64;
  const int t = threadIdx.x;
#pragma unroll
  for (int rep = 0; rep < 8; ++rep) {
    const int li = rep * 256 + t;
    const int k = li >> 5;
    const int d0 = (li & 31) * 4;
    const int g = g0 + k;
    const float* src;
    if (g < 8192)       src = V0 + ((size_t)kvh * 8192 + g) * 128 + d0;
    else if (g < 12288) src = V1 + ((size_t)kvh * 4096 + (g - 8192)) * 128 + d0;
    else                src = V2 + ((size_t)kvh * 2048 + (g - 12288)) * 128 + d0;
    const float4 v = ld4(src);
    h2 x = pk(v.x, v.y), y = pk(v.z, v.w);
    h4 q4; q4[0] = x[0]; q4[1] = x[1]; q4[2] = y[0]; q4[3] = y[1];
    *(h4*)((char*)T + k * 272 + d0 * 2) = q4;
  }
  __syncthreads();
#pragma unroll
  for (int rep = 0; rep < 4; ++rep) {
    const int li = rep * 256 + t;
    const int d = li >> 3;
    const int kc = (li & 7) * 8;
    h8 o;
#pragma unroll
    for (int j = 0; j < 8; ++j) o[j] = T[(kc + j) * 136 + d];
    *(h8*)(Vt + ((size_t)kvh * 128 + d) * 14336 + g0 + kc) = o;
  }
}

// ---------------- barrier-free MFMA flash attention (direct fragments) ----------------
// 8 waves (512 thr): group g=wv>>2 owns q-half g, wave wv&3 owns keys [wk,wk+32).
// K fragments: direct fp32 global loads + in-register f16 convert.
// V fragments: direct h8 loads from f16 Vt cache. NO per-tile barriers/LDS tiles.
// ALL rq[]/acc[] loops FULLY unrolled (rule #20 — R14's partial unroll spilled).
__global__ __launch_bounds__(512, 4) void attn_mfma_kernel(
    const float* __restrict__ q_ws,
    const float* __restrict__ cosT, const float* __restrict__ sinT,
    const float* __restrict__ K0, const float* __restrict__ K1, const float* __restrict__ K2,
    const float* __restrict__ V0, const float* __restrict__ V1, const float* __restrict__ V2,
    const int* __restrict__ loc,
    const f16* __restrict__ Vt, const int vt16,
    float* __restrict__ attn,
    float* __restrict__ Opart, float* __restrict__ Ml, const int NS)
{
  union ShmU {
    f16 rq[64 * 128];                                   // 16 KB, alive in main loop
    struct { float o[2][32 * 132]; float m[8][32]; float l[8][32];
             float lg[2][32]; float mg[2][32]; } e;     // ~38 KB, epilogue only
  };
  __shared__ __align__(16) ShmU S;

  int unit, s, h, w, kvh;
  if (NS > 1) {
    const int C = 4 * NS;
    const int combo = blockIdx.x % C;
    const int idx = blockIdx.x / C;
    kvh = combo / NS; s = combo % NS;
    const int hh7 = idx % 7;
    w = idx / 7;
    h = kvh * 7 + hh7;
    unit = w * 28 + h;
  } else {
    unit = blockIdx.x; s = 0;
    h = unit % 28; w = unit / 28; kvh = h / 7;
  }

  const int tiles_per = 112 / NS;
  const int tile0 = s * tiles_per;
  const int tile1 = tile0 + tiles_per;

  const int t = threadIdx.x;
  const int lane = t & 63;
  const int wv = t >> 6;
  const int g  = wv >> 2;
  const int wg = wv & 3;
  const int wk = wg * 32;
  const int l31 = lane & 31;
  const int hh = lane >> 5;

  const size_t qb = (size_t)unit * 64 * 128;

  const float* K0b = K0 + (size_t)kvh * 8192 * 128;
  const float* K1b = K1 + (size_t)kvh * 4096 * 128;
  const float* K2b = K2 + (size_t)kvh * 2048 * 128;
  const float* V0b = V0 + (size_t)kvh * 8192 * 128;
  const float* V1b = V1 + (size_t)kvh * 4096 * 128;
  const float* V2b = V2 + (size_t)kvh * 2048 * 128;
  const f16* Vtg = Vt ? (Vt + (size_t)kvh * 128 * 14336) : (const f16*)nullptr;

  f32x16 acc[4];
#pragma unroll
  for (int i = 0; i < 4; ++i)
#pragma unroll
    for (int gg = 0; gg < 16; ++gg) acc[i][gg] = 0.f;

  h8 rq[8];
  float m_run = -INFINITY, l_run = 0.f;
  int locq = 0;
  int fprev = -1;

  for (int tile = tile0; tile < tile1; ++tile) {
    int f, rel; const float *Kg, *Vg;
    if (tile < 64)      { f = 0; rel = tile * 128;        Kg = K0b; Vg = V0b; }
    else if (tile < 96) { f = 1; rel = (tile - 64) * 128; Kg = K1b; Vg = V1b; }
    else                { f = 2; rel = (tile - 96) * 128; Kg = K2b; Vg = V2b; }
    const int gcat = tile * 128;
    const bool fsw = (f != fprev);
    fprev = f;

    if (fsw) {
      __syncthreads();               // all waves done reading previous RQ
      const size_t cb = ((size_t)(f * 2 + w)) * 64 * 128;
#pragma unroll
      for (int rep = 0; rep < 2; ++rep) {
        const int qr = rep * 32 + (t >> 4);
        const int d0 = (t & 15) * 8;
        const float* qp = q_ws + qb + (size_t)qr * 128;
        const float4 a0 = ld4(qp + d0), a1 = ld4(qp + d0 + 4);
        const int pd = (d0 < 64) ? d0 + 64 : d0 - 64;
        const float4 r0 = ld4(qp + pd), r1 = ld4(qp + pd + 4);
        const float sg = (d0 < 64) ? -1.f : 1.f;
        const float* cp = cosT + cb + (size_t)qr * 128;
        const float* sp = sinT + cb + (size_t)qr * 128;
        const float4 c0 = ld4(cp + d0), c1 = ld4(cp + d0 + 4);
        const float4 s0 = ld4(sp + d0), s1 = ld4(sp + d0 + 4);
        h8 hv = mk8(pk(a0.x * c0.x + sg * r0.x * s0.x, a0.y * c0.y + sg * r0.y * s0.y),
                    pk(a0.z * c0.z + sg * r0.z * s0.z, a0.w * c0.w + sg * r0.w * s0.w),
                    pk(a1.x * c1.x + sg * r1.x * s1.x, a1.y * c1.y + sg * r1.y * s1.y),
                    pk(a1.z * c1.z + sg * r1.z * s1.z, a1.w * c1.w + sg * r1.w * s1.w));
        *(h8*)((char*)S.rq + qr * 256 + ((d0 * 2) ^ ((qr & 7) << 4))) = hv;
      }
      locq = loc[(f * 2 + w) * 64 + g * 32 + l31];
      __syncthreads();
#pragma unroll
      for (int c = 0; c < 8; ++c)
        rq[c] = *(const h8*)((const char*)S.rq + (g * 32 + l31) * 256 +
                             (((c * 32) + hh * 16) ^ ((l31 & 7) << 4)));
    }

    // ---- QK^T: K fragments direct from global fp32 (convert in-register) ----
    f32x16 sacc;
#pragma unroll
    for (int gg = 0; gg < 16; ++gg) sacc[gg] = 0.f;
    {
      const float* kp = Kg + (size_t)(rel + wk + l31) * 128 + hh * 8;
      __builtin_amdgcn_s_setprio(1);
#pragma unroll
      for (int c = 0; c < 8; ++c) {     // FULL unroll: rq[c] must be static (rule #20)
        const float4 x0 = ld4(kp + c * 16);
        const float4 x1 = ld4(kp + c * 16 + 4);
        const h8 a = mk8(pk(x0.x, x0.y), pk(x0.z, x0.w), pk(x1.x, x1.y), pk(x1.z, x1.w));
        sacc = __builtin_amdgcn_mfma_f32_32x32x16_f16(a, rq[c], sacc, 0, 0, 0);
      }
      __builtin_amdgcn_s_setprio(0);
    }

    // ---- mask + scale + online softmax ----
    float p[16];
    float mt = -INFINITY;
#pragma unroll
    for (int gg = 0; gg < 16; ++gg) {
      const int kl = (gg & 3) + 8 * (gg >> 2) + 4 * hh;
      float z = sacc[gg] * SCALE;
      if (rel + wk + kl > locq) z = -INFINITY;
      p[gg] = z;
      mt = fmaxf(mt, z);
    }
    mt = fmaxf(mt, __shfl_xor(mt, 32, 64));
    if (!__all(mt <= m_run + 8.f)) {        // defer-max (T13)
      const float mn = fmaxf(m_run, mt);
      const float rr = __expf(m_run - mn);
      l_run *= rr;
#pragma unroll
      for (int i = 0; i < 4; ++i)
#pragma unroll
        for (int gg = 0; gg < 16; ++gg) acc[i][gg] *= rr;
      m_run = mn;
    }
    float ls = 0.f;
#pragma unroll
    for (int gg = 0; gg < 16; ++gg) { const float pe = __expf(p[gg] - m_run); p[gg] = pe; ls += pe; }
    l_run += ls + __shfl_xor(ls, 32, 64);

    // ---- P -> f16 B-fragments ----
    h2 wvv[8], xvv[8];
#pragma unroll
    for (int gg = 0; gg < 8; ++gg) wvv[gg] = pk(p[2 * gg], p[2 * gg + 1]);
#pragma unroll
    for (int gg = 0; gg < 8; ++gg) xvv[gg] = sw32(wvv[gg]);
    const h8 bp0 = hh ? mk8(xvv[2], xvv[3], wvv[2], wvv[3]) : mk8(wvv[0], wvv[1], xvv[0], xvv[1]);
    const h8 bp1 = hh ? mk8(xvv[6], xvv[7], wvv[6], wvv[7]) : mk8(wvv[4], wvv[5], xvv[4], xvv[5]);

    // ---- PV: V^T fragments direct from f16 Vt cache (FULL unroll: acc[dt]) ----
    __builtin_amdgcn_s_setprio(1);
    if (vt16) {
#pragma unroll
      for (int dt = 0; dt < 4; ++dt) {
        const f16* vp = Vtg + (size_t)(dt * 32 + l31) * 14336 + gcat + wk + hh * 8;
        const h8 a0 = *(const h8*)vp;
        const h8 a1 = *(const h8*)(vp + 16);
        acc[dt] = __builtin_amdgcn_mfma_f32_32x32x16_f16(a0, bp0, acc[dt], 0, 0, 0);
        acc[dt] = __builtin_amdgcn_mfma_f32_32x32x16_f16(a1, bp1, acc[dt], 0, 0, 0);
      }
    } else {
      // correctness fallback (never exercised with current ws): scalar gather
#pragma unroll
      for (int dt = 0; dt < 4; ++dt) {
        const int d = dt * 32 + l31;
        h8 a0, a1;
#pragma unroll
        for (int j = 0; j < 8; j += 2) {
          const float v0 = Vg[(size_t)(rel + wk + hh * 8 + j) * 128 + d];
          const float v1 = Vg[(size_t)(rel + wk + hh * 8 + j + 1) * 128 + d];
          const h2 x = pk(v0, v1); a0[j] = x[0]; a0[j + 1] = x[1];
          const float u0 = Vg[(size_t)(rel + wk + 16 + hh * 8 + j) * 128 + d];
          const float u1 = Vg[(size_t)(rel + wk + 16 + hh * 8 + j + 1) * 128 + d];
          const h2 y = pk(u0, u1); a1[j] = y[0]; a1[j + 1] = y[1];
        }
        acc[dt] = __builtin_amdgcn_mfma_f32_32x32x16_f16(a0, bp0, acc[dt], 0, 0, 0);
        acc[dt] = __builtin_amdgcn_mfma_f32_32x32x16_f16(a1, bp1, acc[dt], 0, 0, 0);
      }
    }
    __builtin_amdgcn_s_setprio(0);
  }

  // ---- epilogue: per-group cross-wave combine (RQ dead; union with S.e safe) ----
  __syncthreads();
  if (lane < 32) { S.e.m[wv][l31] = m_run; S.e.l[wv][l31] = l_run; }
  {
    const float4 z4 = make_float4(0.f, 0.f, 0.f, 0.f);
    for (int i = t; i < 2 * 32 * 132 / 4; i += 512) ((float4*)S.e.o)[i] = z4;
  }
  __syncthreads();
  float M = -INFINITY;
#pragma unroll
  for (int j = 0; j < 4; ++j) M = fmaxf(M, S.e.m[g * 4 + j][l31]);
  float Lg = 0.f;
#pragma unroll
  for (int j = 0; j < 4; ++j) Lg += S.e.l[g * 4 + j][l31] * __expf(S.e.m[g * 4 + j][l31] - M);
  const float swf = __expf(m_run - M);
  if (wg == 0 && lane < 32) { S.e.lg[g][l31] = Lg; S.e.mg[g][l31] = M; }
  __syncthreads();

#pragma unroll
  for (int r = 0; r < 4; ++r) {
#pragma unroll
    for (int dt = 0; dt < 4; ++dt) {
#pragma unroll
      for (int gq = 0; gq < 4; ++gq) {
        if ((((dt * 2 + (gq >> 1)) - wg - r) & 3) == 0) {   // wave-uniform predicate
          const int db = dt * 32 + 8 * gq + 4 * hh;
          float4* pp = (float4*)&S.e.o[g][l31 * 132 + db];
          float4 v = *pp;
          v.x += acc[dt][gq * 4 + 0] * swf;
          v.y += acc[dt][gq * 4 + 1] * swf;
          v.z += acc[dt][gq * 4 + 2] * swf;
          v.w += acc[dt][gq * 4 + 3] * swf;
          *pp = v;
        }
      }
    }
    __syncthreads();
  }

  {
    const int q = t >> 3;
    const int hf = q >> 5;
    const int qr = q & 31;
    const int d0 = (t & 7) * 16;
    const float* op = &S.e.o[hf][qr * 132 + d0];
    if (NS == 1) {
      const float invl = 1.f / S.e.lg[hf][qr];
      float* dst = attn + ((size_t)(w * 64 + q)) * 3584 + h * 128 + d0;
#pragma unroll
      for (int i = 0; i < 4; ++i)
        st4(dst + 4 * i, make_float4(op[4*i] * invl, op[4*i+1] * invl, op[4*i+2] * invl, op[4*i+3] * invl));
    } else {
      float* dst = Opart + (((size_t)unit * NS + s) * 64 + q) * 128 + d0;
#pragma unroll
      for (int i = 0; i < 4; ++i)
        st4(dst + 4 * i, make_float4(op[4*i], op[4*i+1], op[4*i+2], op[4*i+3]));
      if (t < 64) {
        float* mlp = Ml + ((size_t)unit * NS + s) * 128;
        mlp[t] = S.e.mg[t >> 5][t & 31];
        mlp[64 + t] = S.e.lg[t >> 5][t & 31];
      }
    }
  }
}

// merge NS split partials. grid 56 x 512.
__global__ __launch_bounds__(512) void attn_combine_kernel(
    const float* __restrict__ Opart, const float* __restrict__ Ml,
    float* __restrict__ attn, const int NS)
{
  const int unit = blockIdx.x;
  const int h = unit % 28;
  const int w = unit / 28;
  const int t = threadIdx.x;
  const int q = t >> 3;
  const int d0 = (t & 7) * 16;

  float M = -INFINITY;
  for (int s = 0; s < NS; ++s) M = fmaxf(M, Ml[((size_t)unit * NS + s) * 128 + q]);
  float L = 0.f;
  float acc[16];
#pragma unroll
  for (int i = 0; i < 16; ++i) acc[i] = 0.f;
  for (int s = 0; s < NS; ++s) {
    const float ms = Ml[((size_t)unit * NS + s) * 128 + q];
    const float ls = Ml[((size_t)unit * NS + s) * 128 + 64 + q];
    const float wgt = __expf(ms - M);
    L += ls * wgt;
    const float* op = Opart + (((size_t)unit * NS + s) * 64 + q) * 128 + d0;
#pragma unroll
    for (int i = 0; i < 4; ++i) {
      const float4 v = ld4(op + 4 * i);
      acc[4 * i + 0] += v.x * wgt;
      acc[4 * i + 1] += v.y * wgt;
      acc[4 * i + 2] += v.z * wgt;
      acc[4 * i + 3] += v.w * wgt;
    }
  }
  const float invl = 1.f / L;
  float* dst = attn + ((size_t)(w * 64 + q)) * 3584 + h * 128 + d0;
#pragma unroll
  for (int i = 0; i < 4; ++i) {
    const float4 o = make_float4(acc[4 * i + 0] * invl, acc[4 * i + 1] * invl,
                                 acc[4 * i + 2] * invl, acc[4 * i + 3] * invl);
    st4(dst + 4 * i, o);
  }
}

extern "C" void kernel_launch(void* const* d_in, const int* in_sizes, int n_in,
                              void* d_out, int out_size, void* d_ws, size_t ws_size,
                              hipStream_t stream) {
  (void)n_in; (void)out_size;
  const float* hs = (const float*)d_in[0];
  const float* wq = (const float*)d_in[1];
  const float* bq = (const float*)d_in[2];
  const float* wo = (const float*)d_in[3];

  const float *K0, *V0, *K1, *V1, *K2, *V2, *cosT, *sinT;
  const int* loc;
  if (in_sizes[5] == in_sizes[4]) {  // dict order
    K0 = (const float*)d_in[4]; V0 = (const float*)d_in[5];
    K1 = (const float*)d_in[6]; V1 = (const float*)d_in[7];
    K2 = (const float*)d_in[8]; V2 = (const float*)d_in[9];
    loc = (const int*)d_in[10];
    cosT = (const float*)d_in[11]; sinT = (const float*)d_in[12];
  } else {                            // signature order
    K0 = (const float*)d_in[4]; K1 = (const float*)d_in[5]; K2 = (const float*)d_in[6];
    V0 = (const float*)d_in[7]; V1 = (const float*)d_in[8]; V2 = (const float*)d_in[9];
    cosT = (const float*)d_in[10]; sinT = (const float*)d_in[11];
    loc = (const int*)d_in[12];
  }

  float* outp = (float*)d_out;          // q [w][h][qn][d] between gemm1 and attn
  float* attn = (float*)d_ws;           // [128][3584] = 1,835,008 B
  char* base = (char*)d_ws;

  const size_t ATTN_B = (size_t)458752 * 4;            // 1,835,008
  const size_t RB = (size_t)4 * 128 * 14336 * 2;       // 14,680,064: Vt f16 / Gpart KS=8
  auto opartBytes = [](int ns){ return (size_t)56 * ns * 33280; };

  size_t off = ATTN_B;
  f16* Vt = nullptr; int vt16 = 0;
  float *Opart = nullptr, *Ml = nullptr, *Gpart = nullptr;
  int NS = 1, KS = 1;

  // Region R: Vt (attn phase) / Gpart (gemm phases) — lifetimes disjoint.
  const bool haveR = (ws_size >= off + RB + opartBytes(2));
  if (haveR) {
    Vt = (f16*)(base + off); vt16 = 1;
    Gpart = (float*)(base + off); KS = 8;           // 8 x 1.835 MB = RB exactly
    off += RB;
  }
  for (int cand = 8; cand >= 2; cand >>= 1) {
    if (ws_size >= off + opartBytes(cand)) {
      NS = cand;
      Opart = (float*)(base + off);
      Ml = Opart + (size_t)56 * cand * 64 * 128;
      off += opartBytes(cand);
      break;
    }
  }
  if (!haveR) {
    if (ws_size >= off + (size_t)8 * ATTN_B)      { KS = 8; Gpart = (float*)(base + off); }
    else if (ws_size >= off + (size_t)4 * ATTN_B) { KS = 4; Gpart = (float*)(base + off); }
  }

  // ---- gemm1: q = hs @ wq^T + bq, q-layout (grid x = 3584/64 = 56) ----
  if (KS > 1) {
    gemm_mfma_kernel<<<dim3(56, KS, 1), 256, 0, stream>>>(hs, wq, nullptr, nullptr, 1, Gpart, KS);
    gemm_reduce_kernel<<<448, 256, 0, stream>>>(Gpart, bq, outp, KS, 1);
  } else {
    gemm_mfma_kernel<<<dim3(56, 1, 1), 256, 0, stream>>>(hs, wq, bq, outp, 1, nullptr, 1);
  }

  if (vt16) vtrans_kernel<<<896, 256, 0, stream>>>(V0, V1, V2, Vt);   // after reduce1

  // ---- attention (barrier-free direct fragments, split-K x NS) ----
  const int grid = (NS > 1) ? 56 * NS : 56;
  attn_mfma_kernel<<<grid, 512, 0, stream>>>(
      outp, cosT, sinT, K0, K1, K2, V0, V1, V2, loc, Vt, vt16, attn, Opart, Ml, NS);
  if (NS > 1) attn_combine_kernel<<<56, 512, 0, stream>>>(Opart, Ml, attn, NS);

  // ---- gemm2: out = attn @ wo^T (Gpart overwrites Vt — Vt dead after attn) ----
  if (KS > 1) {
    gemm_mfma_kernel<<<dim3(56, KS, 1), 256, 0, stream>>>(attn, wo, nullptr, nullptr, 0, Gpart, KS);
    gemm_reduce_kernel<<<448, 256, 0, stream>>>(Gpart, nullptr, outp, KS, 0);
  } else {
    gemm_mfma_kernel<<<dim3(56, 1, 1), 256, 0, stream>>>(attn, wo, nullptr, outp, 0, nullptr, 1);
  }
}

// Round 16
// 376.700 us; speedup vs baseline: 1.4085x; 1.3921x over previous
//
#include <hip/hip_runtime.h>
#include <math.h>

// W=2, QN=64, H=28, HKV=4 (G=7), D=128, HID=3584; frags 8192/4096/2048 (Ktot=14336)
// R16: barrier-free attn, register-budget fix. R15 spilled because acc(64)+rq(32)
// +sacc(16)+hoisted K loads(64) >> 128-VGPR cap (launch_bounds 512,4). Fix:
// (1) rq NOT register-cached - Q fragments read from LDS RQ inside the QK loop
//     (LDS addr may be runtime-indexed; frees 32 persistent VGPRs);
// (2) unroll 2 on QK loop (safe now - no register array indexed by c) bounds
//     load hoisting. Peak ~110 VGPR < 128. GATES: attn WRITE<40MB, VGPR>=100;
// else revert to R13. gemm: R13 split-f16 MFMA (proven).

typedef _Float16 f16;
typedef _Float16 h2 __attribute__((ext_vector_type(2)));
typedef _Float16 h4 __attribute__((ext_vector_type(4)));
typedef _Float16 h8 __attribute__((ext_vector_type(8)));
typedef float f32x16 __attribute__((ext_vector_type(16)));

static __device__ __forceinline__ float4 ld4(const float* p){ return *reinterpret_cast<const float4*>(p); }
static __device__ __forceinline__ void st4(float* p, const float4 v){ *reinterpret_cast<float4*>(p) = v; }
static __device__ __forceinline__ h2 pk(float a, float b){
  return __builtin_bit_cast(h2, __builtin_amdgcn_cvt_pkrtz(a, b));
}
static __device__ __forceinline__ h2 sw32(h2 v){
  int i = __builtin_bit_cast(int, v);
  i = __shfl_xor(i, 32, 64);
  return __builtin_bit_cast(h2, i);
}
static __device__ __forceinline__ h8 mk8(h2 a, h2 b, h2 c, h2 d){
  h8 r; r[0]=a[0]; r[1]=a[1]; r[2]=b[0]; r[3]=b[1]; r[4]=c[0]; r[5]=c[1]; r[6]=d[0]; r[7]=d[1]; return r;
}
static __device__ __forceinline__ h4 mk4(h2 a, h2 b){
  h4 r; r[0]=a[0]; r[1]=a[1]; r[2]=b[0]; r[3]=b[1]; return r;
}
static __device__ __forceinline__ h8 ld8h(const f16* p){
  const h4 a = *(const h4*)p;
  const h4 b = *(const h4*)(p + 4);
  h8 r; r[0]=a[0]; r[1]=a[1]; r[2]=a[2]; r[3]=a[3]; r[4]=b[0]; r[5]=b[1]; r[6]=b[2]; r[7]=b[3];
  return r;
}

#define SCALE 0.08838834764831845f

// ---------------- MFMA GEMM, split-f16 3-pass (fp32-accurate, R13 proven) ----------------
__global__ __launch_bounds__(256) void gemm_mfma_kernel(
    const float* __restrict__ A, const float* __restrict__ Bw,
    const float* __restrict__ bias, float* __restrict__ out, const int qlayout,
    float* __restrict__ Gpart, const int KS)
{
  __shared__ __align__(16) f16 Ah[128][68];
  __shared__ __align__(16) f16 Al[128][68];
  __shared__ __align__(16) f16 Bh[64][68];
  __shared__ __align__(16) f16 Bl[64][68];

  const int t = threadIdx.x;
  const int lane = t & 63;
  const int wv = t >> 6;
  const int l31 = lane & 31;
  const int hh = lane >> 5;
  const int nblk = blockIdx.x * 64;
  const int ks = blockIdx.y;
  const int kspan = 3584 / KS;
  const int kbeg = ks * kspan;

  f32x16 acc0, acc1;
#pragma unroll
  for (int g = 0; g < 16; ++g) { acc0[g] = 0.f; acc1[g] = 0.f; }

  for (int kc = kbeg; kc < kbeg + kspan; kc += 64) {
#pragma unroll
    for (int r = 0; r < 4; ++r) {
      const int li = r * 256 + t;
      const int m = li >> 3;
      const int k8 = (li & 7) * 8;
      const float* p = A + (size_t)m * 3584 + kc + k8;
      const float4 x0 = ld4(p), x1 = ld4(p + 4);
      const h2 a01 = pk(x0.x, x0.y), a23 = pk(x0.z, x0.w);
      const h2 a45 = pk(x1.x, x1.y), a67 = pk(x1.z, x1.w);
      const h2 r01 = pk(x0.x - (float)a01[0], x0.y - (float)a01[1]);
      const h2 r23 = pk(x0.z - (float)a23[0], x0.w - (float)a23[1]);
      const h2 r45 = pk(x1.x - (float)a45[0], x1.y - (float)a45[1]);
      const h2 r67 = pk(x1.z - (float)a67[0], x1.w - (float)a67[1]);
      *(h4*)&Ah[m][k8]     = mk4(a01, a23);
      *(h4*)&Ah[m][k8 + 4] = mk4(a45, a67);
      *(h4*)&Al[m][k8]     = mk4(r01, r23);
      *(h4*)&Al[m][k8 + 4] = mk4(r45, r67);
    }
#pragma unroll
    for (int r = 0; r < 2; ++r) {
      const int li = r * 256 + t;
      const int n = li >> 3;
      const int k8 = (li & 7) * 8;
      const float* p = Bw + (size_t)(nblk + n) * 3584 + kc + k8;
      const float4 x0 = ld4(p), x1 = ld4(p + 4);
      const h2 a01 = pk(x0.x, x0.y), a23 = pk(x0.z, x0.w);
      const h2 a45 = pk(x1.x, x1.y), a67 = pk(x1.z, x1.w);
      const h2 r01 = pk(x0.x - (float)a01[0], x0.y - (float)a01[1]);
      const h2 r23 = pk(x0.z - (float)a23[0], x0.w - (float)a23[1]);
      const h2 r45 = pk(x1.x - (float)a45[0], x1.y - (float)a45[1]);
      const h2 r67 = pk(x1.z - (float)a67[0], x1.w - (float)a67[1]);
      *(h4*)&Bh[n][k8]     = mk4(a01, a23);
      *(h4*)&Bh[n][k8 + 4] = mk4(a45, a67);
      *(h4*)&Bl[n][k8]     = mk4(r01, r23);
      *(h4*)&Bl[n][k8 + 4] = mk4(r45, r67);
    }
    __syncthreads();

#pragma unroll 2
    for (int k16 = 0; k16 < 4; ++k16) {
      const int ko = k16 * 16 + hh * 8;
      const h8 ah  = ld8h(&Ah[wv * 32 + l31][ko]);
      const h8 al  = ld8h(&Al[wv * 32 + l31][ko]);
      const h8 bh0 = ld8h(&Bh[l31][ko]);
      const h8 bl0 = ld8h(&Bl[l31][ko]);
      const h8 bh1 = ld8h(&Bh[32 + l31][ko]);
      const h8 bl1 = ld8h(&Bl[32 + l31][ko]);
      acc0 = __builtin_amdgcn_mfma_f32_32x32x16_f16(ah, bh0, acc0, 0, 0, 0);
      acc0 = __builtin_amdgcn_mfma_f32_32x32x16_f16(ah, bl0, acc0, 0, 0, 0);
      acc0 = __builtin_amdgcn_mfma_f32_32x32x16_f16(al, bh0, acc0, 0, 0, 0);
      acc1 = __builtin_amdgcn_mfma_f32_32x32x16_f16(ah, bh1, acc1, 0, 0, 0);
      acc1 = __builtin_amdgcn_mfma_f32_32x32x16_f16(ah, bl1, acc1, 0, 0, 0);
      acc1 = __builtin_amdgcn_mfma_f32_32x32x16_f16(al, bh1, acc1, 0, 0, 0);
    }
    __syncthreads();
  }

  if (Gpart) {
    float* gp = Gpart + (size_t)ks * 458752;
#pragma unroll
    for (int reg = 0; reg < 16; ++reg) {
      const int m = wv * 32 + (reg & 3) + 8 * (reg >> 2) + 4 * hh;
      gp[(size_t)m * 3584 + nblk + l31]      = acc0[reg];
      gp[(size_t)m * 3584 + nblk + 32 + l31] = acc1[reg];
    }
    return;
  }
#pragma unroll
  for (int reg = 0; reg < 16; ++reg) {
    const int m = wv * 32 + (reg & 3) + 8 * (reg >> 2) + 4 * hh;
#pragma unroll
    for (int nt = 0; nt < 2; ++nt) {
      const int n = nblk + nt * 32 + l31;
      float v = (nt ? acc1[reg] : acc0[reg]) + (bias ? bias[n] : 0.f);
      if (qlayout) {
        const int w = m >> 6, qn = m & 63, hcol = n >> 7, d = n & 127;
        out[(((size_t)(w * 28 + hcol)) * 64 + qn) * 128 + d] = v;
      } else {
        out[(size_t)m * 3584 + n] = v;
      }
    }
  }
}

// reduce KS partials, add bias, apply layout. grid 448 x 256 (one float4 each).
__global__ __launch_bounds__(256) void gemm_reduce_kernel(
    const float* __restrict__ Gpart, const float* __restrict__ bias,
    float* __restrict__ out, const int KS, const int qlayout)
{
  const int idx = blockIdx.x * 256 + threadIdx.x;
  const int m = idx / 896;
  const int n = (idx - m * 896) * 4;
  float4 a = ld4(Gpart + (size_t)m * 3584 + n);
  for (int ss = 1; ss < KS; ++ss) {
    const float4 b = ld4(Gpart + (size_t)ss * 458752 + (size_t)m * 3584 + n);
    a.x += b.x; a.y += b.y; a.z += b.z; a.w += b.w;
  }
  if (bias) { a.x += bias[n]; a.y += bias[n + 1]; a.z += bias[n + 2]; a.w += bias[n + 3]; }
  if (qlayout) {
    const int w = m >> 6, qn = m & 63, hh = n >> 7, d = n & 127;
    st4(out + (((size_t)(w * 28 + hh)) * 64 + qn) * 128 + d, a);
  } else {
    st4(out + (size_t)m * 3584 + n, a);
  }
}

// ---------------- pre-pass: V -> f16 transposed [kvh][128][14336] ----------------
__global__ __launch_bounds__(256) void vtrans_kernel(
    const float* __restrict__ V0, const float* __restrict__ V1, const float* __restrict__ V2,
    f16* __restrict__ Vt)
{
  __shared__ __align__(16) f16 T[64 * 136];
  const int bid = blockIdx.x;
  const int kvh = bid / 224;
  const int g0 = (bid % 224) * 64;
  const int t = threadIdx.x;
#pragma unroll
  for (int rep = 0; rep < 8; ++rep) {
    const int li = rep * 256 + t;
    const int k = li >> 5;
    const int d0 = (li & 31) * 4;
    const int g = g0 + k;
    const float* src;
    if (g < 8192)       src = V0 + ((size_t)kvh * 8192 + g) * 128 + d0;
    else if (g < 12288) src = V1 + ((size_t)kvh * 4096 + (g - 8192)) * 128 + d0;
    else                src = V2 + ((size_t)kvh * 2048 + (g - 12288)) * 128 + d0;
    const float4 v = ld4(src);
    h2 x = pk(v.x, v.y), y = pk(v.z, v.w);
    h4 q4; q4[0] = x[0]; q4[1] = x[1]; q4[2] = y[0]; q4[3] = y[1];
    *(h4*)((char*)T + k * 272 + d0 * 2) = q4;
  }
  __syncthreads();
#pragma unroll
  for (int rep = 0; rep < 4; ++rep) {
    const int li = rep * 256 + t;
    const int d = li >> 3;
    const int kc = (li & 7) * 8;
    h8 o;
#pragma unroll
    for (int j = 0; j < 8; ++j) o[j] = T[(kc + j) * 136 + d];
    *(h8*)(Vt + ((size_t)kvh * 128 + d) * 14336 + g0 + kc) = o;
  }
}

// ---------------- barrier-free MFMA flash attention (direct fragments) ----------------
// 8 waves (512 thr): group g=wv>>2 owns q-half g, wave wv&3 owns keys [wk,wk+32).
// K fragments: direct fp32 global loads + in-register f16 convert.
// Q fragments: read from LDS RQ inside the QK loop (NOT register-cached — R15's
// rq[8] cache pushed state over the 128-VGPR cap and spilled acc to scratch).
// V fragments: direct h8 loads from f16 Vt cache. NO per-tile barriers.
__global__ __launch_bounds__(512, 4) void attn_mfma_kernel(
    const float* __restrict__ q_ws,
    const float* __restrict__ cosT, const float* __restrict__ sinT,
    const float* __restrict__ K0, const float* __restrict__ K1, const float* __restrict__ K2,
    const float* __restrict__ V0, const float* __restrict__ V1, const float* __restrict__ V2,
    const int* __restrict__ loc,
    const f16* __restrict__ Vt, const int vt16,
    float* __restrict__ attn,
    float* __restrict__ Opart, float* __restrict__ Ml, const int NS)
{
  union ShmU {
    f16 rq[64 * 128];                                   // 16 KB, alive in main loop
    struct { float o[2][32 * 132]; float m[8][32]; float l[8][32];
             float lg[2][32]; float mg[2][32]; } e;     // ~38 KB, epilogue only
  };
  __shared__ __align__(16) ShmU S;

  int unit, s, h, w, kvh;
  if (NS > 1) {
    const int C = 4 * NS;
    const int combo = blockIdx.x % C;
    const int idx = blockIdx.x / C;
    kvh = combo / NS; s = combo % NS;
    const int hh7 = idx % 7;
    w = idx / 7;
    h = kvh * 7 + hh7;
    unit = w * 28 + h;
  } else {
    unit = blockIdx.x; s = 0;
    h = unit % 28; w = unit / 28; kvh = h / 7;
  }

  const int tiles_per = 112 / NS;
  const int tile0 = s * tiles_per;
  const int tile1 = tile0 + tiles_per;

  const int t = threadIdx.x;
  const int lane = t & 63;
  const int wv = t >> 6;
  const int g  = wv >> 2;
  const int wg = wv & 3;
  const int wk = wg * 32;
  const int l31 = lane & 31;
  const int hh = lane >> 5;

  const size_t qb = (size_t)unit * 64 * 128;

  const float* K0b = K0 + (size_t)kvh * 8192 * 128;
  const float* K1b = K1 + (size_t)kvh * 4096 * 128;
  const float* K2b = K2 + (size_t)kvh * 2048 * 128;
  const float* V0b = V0 + (size_t)kvh * 8192 * 128;
  const float* V1b = V1 + (size_t)kvh * 4096 * 128;
  const float* V2b = V2 + (size_t)kvh * 2048 * 128;
  const f16* Vtg = Vt ? (Vt + (size_t)kvh * 128 * 14336) : (const f16*)nullptr;

  f32x16 acc[4];
#pragma unroll
  for (int i = 0; i < 4; ++i)
#pragma unroll
    for (int gg = 0; gg < 16; ++gg) acc[i][gg] = 0.f;

  float m_run = -INFINITY, l_run = 0.f;
  int locq = 0;
  int fprev = -1;

  // per-thread constant part of the RQ read address (byte offset)
  const char* rqbase = (const char*)S.rq + (g * 32 + l31) * 256;
  const int rqxor = (l31 & 7) << 4;

  for (int tile = tile0; tile < tile1; ++tile) {
    int f, rel; const float *Kg, *Vg;
    if (tile < 64)      { f = 0; rel = tile * 128;        Kg = K0b; Vg = V0b; }
    else if (tile < 96) { f = 1; rel = (tile - 64) * 128; Kg = K1b; Vg = V1b; }
    else                { f = 2; rel = (tile - 96) * 128; Kg = K2b; Vg = V2b; }
    const int gcat = tile * 128;
    const bool fsw = (f != fprev);
    fprev = f;

    if (fsw) {
      __syncthreads();               // all waves done reading previous RQ
      const size_t cb = ((size_t)(f * 2 + w)) * 64 * 128;
#pragma unroll
      for (int rep = 0; rep < 2; ++rep) {
        const int qr = rep * 32 + (t >> 4);
        const int d0 = (t & 15) * 8;
        const float* qp = q_ws + qb + (size_t)qr * 128;
        const float4 a0 = ld4(qp + d0), a1 = ld4(qp + d0 + 4);
        const int pd = (d0 < 64) ? d0 + 64 : d0 - 64;
        const float4 r0 = ld4(qp + pd), r1 = ld4(qp + pd + 4);
        const float sg = (d0 < 64) ? -1.f : 1.f;
        const float* cp = cosT + cb + (size_t)qr * 128;
        const float* sp = sinT + cb + (size_t)qr * 128;
        const float4 c0 = ld4(cp + d0), c1 = ld4(cp + d0 + 4);
        const float4 s0 = ld4(sp + d0), s1 = ld4(sp + d0 + 4);
        h8 hv = mk8(pk(a0.x * c0.x + sg * r0.x * s0.x, a0.y * c0.y + sg * r0.y * s0.y),
                    pk(a0.z * c0.z + sg * r0.z * s0.z, a0.w * c0.w + sg * r0.w * s0.w),
                    pk(a1.x * c1.x + sg * r1.x * s1.x, a1.y * c1.y + sg * r1.y * s1.y),
                    pk(a1.z * c1.z + sg * r1.z * s1.z, a1.w * c1.w + sg * r1.w * s1.w));
        *(h8*)((char*)S.rq + qr * 256 + ((d0 * 2) ^ ((qr & 7) << 4))) = hv;
      }
      locq = loc[(f * 2 + w) * 64 + g * 32 + l31];
      __syncthreads();
    }

    // ---- QK^T: K direct from global fp32; Q fragment from LDS per iteration ----
    f32x16 sacc;
#pragma unroll
    for (int gg = 0; gg < 16; ++gg) sacc[gg] = 0.f;
    {
      const float* kp = Kg + (size_t)(rel + wk + l31) * 128 + hh * 8;
      __builtin_amdgcn_s_setprio(1);
#pragma unroll 2
      for (int c = 0; c < 8; ++c) {
        const float4 x0 = ld4(kp + c * 16);
        const float4 x1 = ld4(kp + c * 16 + 4);
        const h8 q = *(const h8*)(rqbase + ((c * 32 + hh * 16) ^ rqxor));  // LDS b128
        const h8 a = mk8(pk(x0.x, x0.y), pk(x0.z, x0.w), pk(x1.x, x1.y), pk(x1.z, x1.w));
        sacc = __builtin_amdgcn_mfma_f32_32x32x16_f16(a, q, sacc, 0, 0, 0);
      }
      __builtin_amdgcn_s_setprio(0);
    }

    // ---- mask + scale + online softmax ----
    float p[16];
    float mt = -INFINITY;
#pragma unroll
    for (int gg = 0; gg < 16; ++gg) {
      const int kl = (gg & 3) + 8 * (gg >> 2) + 4 * hh;
      float z = sacc[gg] * SCALE;
      if (rel + wk + kl > locq) z = -INFINITY;
      p[gg] = z;
      mt = fmaxf(mt, z);
    }
    mt = fmaxf(mt, __shfl_xor(mt, 32, 64));
    if (!__all(mt <= m_run + 8.f)) {        // defer-max (T13)
      const float mn = fmaxf(m_run, mt);
      const float rr = __expf(m_run - mn);
      l_run *= rr;
#pragma unroll
      for (int i = 0; i < 4; ++i)
#pragma unroll
        for (int gg = 0; gg < 16; ++gg) acc[i][gg] *= rr;
      m_run = mn;
    }
    float ls = 0.f;
#pragma unroll
    for (int gg = 0; gg < 16; ++gg) { const float pe = __expf(p[gg] - m_run); p[gg] = pe; ls += pe; }
    l_run += ls + __shfl_xor(ls, 32, 64);

    // ---- P -> f16 B-fragments ----
    h2 wvv[8], xvv[8];
#pragma unroll
    for (int gg = 0; gg < 8; ++gg) wvv[gg] = pk(p[2 * gg], p[2 * gg + 1]);
#pragma unroll
    for (int gg = 0; gg < 8; ++gg) xvv[gg] = sw32(wvv[gg]);
    const h8 bp0 = hh ? mk8(xvv[2], xvv[3], wvv[2], wvv[3]) : mk8(wvv[0], wvv[1], xvv[0], xvv[1]);
    const h8 bp1 = hh ? mk8(xvv[6], xvv[7], wvv[6], wvv[7]) : mk8(wvv[4], wvv[5], xvv[4], xvv[5]);

    // ---- PV: V^T fragments direct from f16 Vt cache (FULL unroll: acc[dt]) ----
    __builtin_amdgcn_s_setprio(1);
    if (vt16) {
#pragma unroll
      for (int dt = 0; dt < 4; ++dt) {
        const f16* vp = Vtg + (size_t)(dt * 32 + l31) * 14336 + gcat + wk + hh * 8;
        const h8 a0 = *(const h8*)vp;
        const h8 a1 = *(const h8*)(vp + 16);
        acc[dt] = __builtin_amdgcn_mfma_f32_32x32x16_f16(a0, bp0, acc[dt], 0, 0, 0);
        acc[dt] = __builtin_amdgcn_mfma_f32_32x32x16_f16(a1, bp1, acc[dt], 0, 0, 0);
      }
    } else {
      // correctness fallback (never exercised with current ws): scalar gather
#pragma unroll
      for (int dt = 0; dt < 4; ++dt) {
        const int d = dt * 32 + l31;
        h8 a0, a1;
#pragma unroll
        for (int j = 0; j < 8; j += 2) {
          const float v0 = Vg[(size_t)(rel + wk + hh * 8 + j) * 128 + d];
          const float v1 = Vg[(size_t)(rel + wk + hh * 8 + j + 1) * 128 + d];
          const h2 x = pk(v0, v1); a0[j] = x[0]; a0[j + 1] = x[1];
          const float u0 = Vg[(size_t)(rel + wk + 16 + hh * 8 + j) * 128 + d];
          const float u1 = Vg[(size_t)(rel + wk + 16 + hh * 8 + j + 1) * 128 + d];
          const h2 y = pk(u0, u1); a1[j] = y[0]; a1[j + 1] = y[1];
        }
        acc[dt] = __builtin_amdgcn_mfma_f32_32x32x16_f16(a0, bp0, acc[dt], 0, 0, 0);
        acc[dt] = __builtin_amdgcn_mfma_f32_32x32x16_f16(a1, bp1, acc[dt], 0, 0, 0);
      }
    }
    __builtin_amdgcn_s_setprio(0);
  }

  // ---- epilogue: per-group cross-wave combine (RQ dead; union with S.e safe) ----
  __syncthreads();
  if (lane < 32) { S.e.m[wv][l31] = m_run; S.e.l[wv][l31] = l_run; }
  {
    const float4 z4 = make_float4(0.f, 0.f, 0.f, 0.f);
    for (int i = t; i < 2 * 32 * 132 / 4; i += 512) ((float4*)S.e.o)[i] = z4;
  }
  __syncthreads();
  float M = -INFINITY;
#pragma unroll
  for (int j = 0; j < 4; ++j) M = fmaxf(M, S.e.m[g * 4 + j][l31]);
  float Lg = 0.f;
#pragma unroll
  for (int j = 0; j < 4; ++j) Lg += S.e.l[g * 4 + j][l31] * __expf(S.e.m[g * 4 + j][l31] - M);
  const float swf = __expf(m_run - M);
  if (wg == 0 && lane < 32) { S.e.lg[g][l31] = Lg; S.e.mg[g][l31] = M; }
  __syncthreads();

#pragma unroll
  for (int r = 0; r < 4; ++r) {
#pragma unroll
    for (int dt = 0; dt < 4; ++dt) {
#pragma unroll
      for (int gq = 0; gq < 4; ++gq) {
        if ((((dt * 2 + (gq >> 1)) - wg - r) & 3) == 0) {   // wave-uniform predicate
          const int db = dt * 32 + 8 * gq + 4 * hh;
          float4* pp = (float4*)&S.e.o[g][l31 * 132 + db];
          float4 v = *pp;
          v.x += acc[dt][gq * 4 + 0] * swf;
          v.y += acc[dt][gq * 4 + 1] * swf;
          v.z += acc[dt][gq * 4 + 2] * swf;
          v.w += acc[dt][gq * 4 + 3] * swf;
          *pp = v;
        }
      }
    }
    __syncthreads();
  }

  {
    const int q = t >> 3;
    const int hf = q >> 5;
    const int qr = q & 31;
    const int d0 = (t & 7) * 16;
    const float* op = &S.e.o[hf][qr * 132 + d0];
    if (NS == 1) {
      const float invl = 1.f / S.e.lg[hf][qr];
      float* dst = attn + ((size_t)(w * 64 + q)) * 3584 + h * 128 + d0;
#pragma unroll
      for (int i = 0; i < 4; ++i)
        st4(dst + 4 * i, make_float4(op[4*i] * invl, op[4*i+1] * invl, op[4*i+2] * invl, op[4*i+3] * invl));
    } else {
      float* dst = Opart + (((size_t)unit * NS + s) * 64 + q) * 128 + d0;
#pragma unroll
      for (int i = 0; i < 4; ++i)
        st4(dst + 4 * i, make_float4(op[4*i], op[4*i+1], op[4*i+2], op[4*i+3]));
      if (t < 64) {
        float* mlp = Ml + ((size_t)unit * NS + s) * 128;
        mlp[t] = S.e.mg[t >> 5][t & 31];
        mlp[64 + t] = S.e.lg[t >> 5][t & 31];
      }
    }
  }
}

// merge NS split partials. grid 56 x 512.
__global__ __launch_bounds__(512) void attn_combine_kernel(
    const float* __restrict__ Opart, const float* __restrict__ Ml,
    float* __restrict__ attn, const int NS)
{
  const int unit = blockIdx.x;
  const int h = unit % 28;
  const int w = unit / 28;
  const int t = threadIdx.x;
  const int q = t >> 3;
  const int d0 = (t & 7) * 16;

  float M = -INFINITY;
  for (int s = 0; s < NS; ++s) M = fmaxf(M, Ml[((size_t)unit * NS + s) * 128 + q]);
  float L = 0.f;
  float acc[16];
#pragma unroll
  for (int i = 0; i < 16; ++i) acc[i] = 0.f;
  for (int s = 0; s < NS; ++s) {
    const float ms = Ml[((size_t)unit * NS + s) * 128 + q];
    const float ls = Ml[((size_t)unit * NS + s) * 128 + 64 + q];
    const float wgt = __expf(ms - M);
    L += ls * wgt;
    const float* op = Opart + (((size_t)unit * NS + s) * 64 + q) * 128 + d0;
#pragma unroll
    for (int i = 0; i < 4; ++i) {
      const float4 v = ld4(op + 4 * i);
      acc[4 * i + 0] += v.x * wgt;
      acc[4 * i + 1] += v.y * wgt;
      acc[4 * i + 2] += v.z * wgt;
      acc[4 * i + 3] += v.w * wgt;
    }
  }
  const float invl = 1.f / L;
  float* dst = attn + ((size_t)(w * 64 + q)) * 3584 + h * 128 + d0;
#pragma unroll
  for (int i = 0; i < 4; ++i) {
    const float4 o = make_float4(acc[4 * i + 0] * invl, acc[4 * i + 1] * invl,
                                 acc[4 * i + 2] * invl, acc[4 * i + 3] * invl);
    st4(dst + 4 * i, o);
  }
}

extern "C" void kernel_launch(void* const* d_in, const int* in_sizes, int n_in,
                              void* d_out, int out_size, void* d_ws, size_t ws_size,
                              hipStream_t stream) {
  (void)n_in; (void)out_size;
  const float* hs = (const float*)d_in[0];
  const float* wq = (const float*)d_in[1];
  const float* bq = (const float*)d_in[2];
  const float* wo = (const float*)d_in[3];

  const float *K0, *V0, *K1, *V1, *K2, *V2, *cosT, *sinT;
  const int* loc;
  if (in_sizes[5] == in_sizes[4]) {  // dict order
    K0 = (const float*)d_in[4]; V0 = (const float*)d_in[5];
    K1 = (const float*)d_in[6]; V1 = (const float*)d_in[7];
    K2 = (const float*)d_in[8]; V2 = (const float*)d_in[9];
    loc = (const int*)d_in[10];
    cosT = (const float*)d_in[11]; sinT = (const float*)d_in[12];
  } else {                            // signature order
    K0 = (const float*)d_in[4]; K1 = (const float*)d_in[5]; K2 = (const float*)d_in[6];
    V0 = (const float*)d_in[7]; V1 = (const float*)d_in[8]; V2 = (const float*)d_in[9];
    cosT = (const float*)d_in[10]; sinT = (const float*)d_in[11];
    loc = (const int*)d_in[12];
  }

  float* outp = (float*)d_out;          // q [w][h][qn][d] between gemm1 and attn
  float* attn = (float*)d_ws;           // [128][3584] = 1,835,008 B
  char* base = (char*)d_ws;

  const size_t ATTN_B = (size_t)458752 * 4;            // 1,835,008
  const size_t RB = (size_t)4 * 128 * 14336 * 2;       // 14,680,064: Vt f16 / Gpart KS=8
  auto opartBytes = [](int ns){ return (size_t)56 * ns * 33280; };

  size_t off = ATTN_B;
  f16* Vt = nullptr; int vt16 = 0;
  float *Opart = nullptr, *Ml = nullptr, *Gpart = nullptr;
  int NS = 1, KS = 1;

  // Region R: Vt (attn phase) / Gpart (gemm phases) — lifetimes disjoint.
  const bool haveR = (ws_size >= off + RB + opartBytes(2));
  if (haveR) {
    Vt = (f16*)(base + off); vt16 = 1;
    Gpart = (float*)(base + off); KS = 8;           // 8 x 1.835 MB = RB exactly
    off += RB;
  }
  for (int cand = 8; cand >= 2; cand >>= 1) {
    if (ws_size >= off + opartBytes(cand)) {
      NS = cand;
      Opart = (float*)(base + off);
      Ml = Opart + (size_t)56 * cand * 64 * 128;
      off += opartBytes(cand);
      break;
    }
  }
  if (!haveR) {
    if (ws_size >= off + (size_t)8 * ATTN_B)      { KS = 8; Gpart = (float*)(base + off); }
    else if (ws_size >= off + (size_t)4 * ATTN_B) { KS = 4; Gpart = (float*)(base + off); }
  }

  // ---- gemm1: q = hs @ wq^T + bq, q-layout (grid x = 3584/64 = 56) ----
  if (KS > 1) {
    gemm_mfma_kernel<<<dim3(56, KS, 1), 256, 0, stream>>>(hs, wq, nullptr, nullptr, 1, Gpart, KS);
    gemm_reduce_kernel<<<448, 256, 0, stream>>>(Gpart, bq, outp, KS, 1);
  } else {
    gemm_mfma_kernel<<<dim3(56, 1, 1), 256, 0, stream>>>(hs, wq, bq, outp, 1, nullptr, 1);
  }

  if (vt16) vtrans_kernel<<<896, 256, 0, stream>>>(V0, V1, V2, Vt);   // after reduce1

  // ---- attention (barrier-free direct fragments, split-K x NS) ----
  const int grid = (NS > 1) ? 56 * NS : 56;
  attn_mfma_kernel<<<grid, 512, 0, stream>>>(
      outp, cosT, sinT, K0, K1, K2, V0, V1, V2, loc, Vt, vt16, attn, Opart, Ml, NS);
  if (NS > 1) attn_combine_kernel<<<56, 512, 0, stream>>>(Opart, Ml, attn, NS);

  // ---- gemm2: out = attn @ wo^T (Gpart overwrites Vt — Vt dead after attn) ----
  if (KS > 1) {
    gemm_mfma_kernel<<<dim3(56, KS, 1), 256, 0, stream>>>(attn, wo, nullptr, nullptr, 0, Gpart, KS);
    gemm_reduce_kernel<<<448, 256, 0, stream>>>(Gpart, nullptr, outp, KS, 0);
  } else {
    gemm_mfma_kernel<<<dim3(56, 1, 1), 256, 0, stream>>>(attn, wo, nullptr, outp, 0, nullptr, 1);
  }
}

// Round 17
// 229.107 us; speedup vs baseline: 2.3159x; 1.6442x over previous
//
#include <hip/hip_runtime.h>
#include <math.h>

// W=2, QN=64, H=28, HKV=4 (G=7), D=128, HID=3584; frags 8192/4096/2048 (Ktot=14336)
// R17: exact revert to R13 (230.4us proven best). The barrier-free branch
// (R14-R16) spilled 3x: the attn kernel's arch-VGPR budget is 64 (acc in AGPRs)
// and the de-staged variant's VALU working set doesn't fit it. R13's staged
// structure does. gemm: split-f16 MFMA 3-pass; attn: R7 staged flash.

typedef _Float16 f16;
typedef _Float16 h2 __attribute__((ext_vector_type(2)));
typedef _Float16 h4 __attribute__((ext_vector_type(4)));
typedef _Float16 h8 __attribute__((ext_vector_type(8)));
typedef float f32x16 __attribute__((ext_vector_type(16)));

static __device__ __forceinline__ float4 ld4(const float* p){ return *reinterpret_cast<const float4*>(p); }
static __device__ __forceinline__ void st4(float* p, const float4 v){ *reinterpret_cast<float4*>(p) = v; }
static __device__ __forceinline__ h2 pk(float a, float b){
  return __builtin_bit_cast(h2, __builtin_amdgcn_cvt_pkrtz(a, b));
}
static __device__ __forceinline__ h2 sw32(h2 v){
  int i = __builtin_bit_cast(int, v);
  i = __shfl_xor(i, 32, 64);
  return __builtin_bit_cast(h2, i);
}
static __device__ __forceinline__ h8 mk8(h2 a, h2 b, h2 c, h2 d){
  h8 r; r[0]=a[0]; r[1]=a[1]; r[2]=b[0]; r[3]=b[1]; r[4]=c[0]; r[5]=c[1]; r[6]=d[0]; r[7]=d[1]; return r;
}
static __device__ __forceinline__ h4 mk4(h2 a, h2 b){
  h4 r; r[0]=a[0]; r[1]=a[1]; r[2]=b[0]; r[3]=b[1]; return r;
}
// 8B-aligned h8 load as two h4 (rows are 136B => only 8B alignment guaranteed)
static __device__ __forceinline__ h8 ld8h(const f16* p){
  const h4 a = *(const h4*)p;
  const h4 b = *(const h4*)(p + 4);
  h8 r; r[0]=a[0]; r[1]=a[1]; r[2]=a[2]; r[3]=a[3]; r[4]=b[0]; r[5]=b[1]; r[6]=b[2]; r[7]=b[3];
  return r;
}

#define SCALE 0.08838834764831845f

// ---------------- MFMA GEMM, split-f16 3-pass (fp32-accurate) ----------------
// C[128 x 3584] = A[128 x 3584] . Bw[3584 x 3584]^T, K-split across blockIdx.y.
// Tile: M=128 (whole), N=64, K-step=64. 4 waves; wave wv owns m-tile wv (32 rows)
// x both n-tiles. acc0/acc1 = f32x16 each. Fragment/output layouts identical to
// the attn kernel's proven 32x32x16 mappings.
__global__ __launch_bounds__(256) void gemm_mfma_kernel(
    const float* __restrict__ A, const float* __restrict__ Bw,
    const float* __restrict__ bias, float* __restrict__ out, const int qlayout,
    float* __restrict__ Gpart, const int KS)
{
  __shared__ __align__(16) f16 Ah[128][68];
  __shared__ __align__(16) f16 Al[128][68];
  __shared__ __align__(16) f16 Bh[64][68];
  __shared__ __align__(16) f16 Bl[64][68];

  const int t = threadIdx.x;
  const int lane = t & 63;
  const int wv = t >> 6;          // 0..3 = m-tile
  const int l31 = lane & 31;
  const int hh = lane >> 5;
  const int nblk = blockIdx.x * 64;
  const int ks = blockIdx.y;
  const int kspan = 3584 / KS;    // KS=8 -> 448 (7 K-steps); KS=1 -> 3584
  const int kbeg = ks * kspan;

  f32x16 acc0, acc1;
#pragma unroll
  for (int g = 0; g < 16; ++g) { acc0[g] = 0.f; acc1[g] = 0.f; }

  for (int kc = kbeg; kc < kbeg + kspan; kc += 64) {
    // ---- stage A (128x64): hi/lo split, 4 reps x 256 thr x 8 elems ----
#pragma unroll
    for (int r = 0; r < 4; ++r) {
      const int li = r * 256 + t;
      const int m = li >> 3;
      const int k8 = (li & 7) * 8;
      const float* p = A + (size_t)m * 3584 + kc + k8;
      const float4 x0 = ld4(p), x1 = ld4(p + 4);
      const h2 a01 = pk(x0.x, x0.y), a23 = pk(x0.z, x0.w);
      const h2 a45 = pk(x1.x, x1.y), a67 = pk(x1.z, x1.w);
      const h2 r01 = pk(x0.x - (float)a01[0], x0.y - (float)a01[1]);
      const h2 r23 = pk(x0.z - (float)a23[0], x0.w - (float)a23[1]);
      const h2 r45 = pk(x1.x - (float)a45[0], x1.y - (float)a45[1]);
      const h2 r67 = pk(x1.z - (float)a67[0], x1.w - (float)a67[1]);
      *(h4*)&Ah[m][k8]     = mk4(a01, a23);
      *(h4*)&Ah[m][k8 + 4] = mk4(a45, a67);
      *(h4*)&Al[m][k8]     = mk4(r01, r23);
      *(h4*)&Al[m][k8 + 4] = mk4(r45, r67);
    }
    // ---- stage B (64x64): hi/lo split, 2 reps ----
#pragma unroll
    for (int r = 0; r < 2; ++r) {
      const int li = r * 256 + t;
      const int n = li >> 3;
      const int k8 = (li & 7) * 8;
      const float* p = Bw + (size_t)(nblk + n) * 3584 + kc + k8;
      const float4 x0 = ld4(p), x1 = ld4(p + 4);
      const h2 a01 = pk(x0.x, x0.y), a23 = pk(x0.z, x0.w);
      const h2 a45 = pk(x1.x, x1.y), a67 = pk(x1.z, x1.w);
      const h2 r01 = pk(x0.x - (float)a01[0], x0.y - (float)a01[1]);
      const h2 r23 = pk(x0.z - (float)a23[0], x0.w - (float)a23[1]);
      const h2 r45 = pk(x1.x - (float)a45[0], x1.y - (float)a45[1]);
      const h2 r67 = pk(x1.z - (float)a67[0], x1.w - (float)a67[1]);
      *(h4*)&Bh[n][k8]     = mk4(a01, a23);
      *(h4*)&Bh[n][k8 + 4] = mk4(a45, a67);
      *(h4*)&Bl[n][k8]     = mk4(r01, r23);
      *(h4*)&Bl[n][k8 + 4] = mk4(r45, r67);
    }
    __syncthreads();

    // ---- 4 x K16 MFMA: 3-pass split accumulate ----
#pragma unroll 2
    for (int k16 = 0; k16 < 4; ++k16) {
      const int ko = k16 * 16 + hh * 8;
      const h8 ah  = ld8h(&Ah[wv * 32 + l31][ko]);
      const h8 al  = ld8h(&Al[wv * 32 + l31][ko]);
      const h8 bh0 = ld8h(&Bh[l31][ko]);
      const h8 bl0 = ld8h(&Bl[l31][ko]);
      const h8 bh1 = ld8h(&Bh[32 + l31][ko]);
      const h8 bl1 = ld8h(&Bl[32 + l31][ko]);
      acc0 = __builtin_amdgcn_mfma_f32_32x32x16_f16(ah, bh0, acc0, 0, 0, 0);
      acc0 = __builtin_amdgcn_mfma_f32_32x32x16_f16(ah, bl0, acc0, 0, 0, 0);
      acc0 = __builtin_amdgcn_mfma_f32_32x32x16_f16(al, bh0, acc0, 0, 0, 0);
      acc1 = __builtin_amdgcn_mfma_f32_32x32x16_f16(ah, bh1, acc1, 0, 0, 0);
      acc1 = __builtin_amdgcn_mfma_f32_32x32x16_f16(ah, bl1, acc1, 0, 0, 0);
      acc1 = __builtin_amdgcn_mfma_f32_32x32x16_f16(al, bh1, acc1, 0, 0, 0);
    }
    __syncthreads();
  }

  // ---- epilogue: D layout col=l31, row=(reg&3)+8*(reg>>2)+4*hh (proven in attn) ----
  if (Gpart) {
    float* gp = Gpart + (size_t)ks * 458752;
#pragma unroll
    for (int reg = 0; reg < 16; ++reg) {
      const int m = wv * 32 + (reg & 3) + 8 * (reg >> 2) + 4 * hh;
      gp[(size_t)m * 3584 + nblk + l31]      = acc0[reg];
      gp[(size_t)m * 3584 + nblk + 32 + l31] = acc1[reg];
    }
    return;
  }
#pragma unroll
  for (int reg = 0; reg < 16; ++reg) {
    const int m = wv * 32 + (reg & 3) + 8 * (reg >> 2) + 4 * hh;
#pragma unroll
    for (int nt = 0; nt < 2; ++nt) {
      const int n = nblk + nt * 32 + l31;
      float v = (nt ? acc1[reg] : acc0[reg]) + (bias ? bias[n] : 0.f);
      if (qlayout) {
        const int w = m >> 6, qn = m & 63, hcol = n >> 7, d = n & 127;
        out[(((size_t)(w * 28 + hcol)) * 64 + qn) * 128 + d] = v;
      } else {
        out[(size_t)m * 3584 + n] = v;
      }
    }
  }
}

// reduce KS partials, add bias, apply layout. grid 448 x 256 (one float4 each).
__global__ __launch_bounds__(256) void gemm_reduce_kernel(
    const float* __restrict__ Gpart, const float* __restrict__ bias,
    float* __restrict__ out, const int KS, const int qlayout)
{
  const int idx = blockIdx.x * 256 + threadIdx.x;   // [0, 114688)
  const int m = idx / 896;                          // 3584/4 float4 per row
  const int n = (idx - m * 896) * 4;
  float4 a = ld4(Gpart + (size_t)m * 3584 + n);
  for (int ss = 1; ss < KS; ++ss) {
    const float4 b = ld4(Gpart + (size_t)ss * 458752 + (size_t)m * 3584 + n);
    a.x += b.x; a.y += b.y; a.z += b.z; a.w += b.w;
  }
  if (bias) { a.x += bias[n]; a.y += bias[n + 1]; a.z += bias[n + 2]; a.w += bias[n + 3]; }
  if (qlayout) {
    const int w = m >> 6, qn = m & 63, hh = n >> 7, d = n & 127;
    st4(out + (((size_t)(w * 28 + hh)) * 64 + qn) * 128 + d, a);
  } else {
    st4(out + (size_t)m * 3584 + n, a);
  }
}

// ---------------- pre-pass: V -> f16 transposed [kvh][128][14336] ----------------
__global__ __launch_bounds__(256) void vtrans_kernel(
    const float* __restrict__ V0, const float* __restrict__ V1, const float* __restrict__ V2,
    f16* __restrict__ Vt)
{
  __shared__ __align__(16) f16 T[64 * 136];
  const int bid = blockIdx.x;          // kvh*224 + chunk
  const int kvh = bid / 224;
  const int g0 = (bid % 224) * 64;
  const int t = threadIdx.x;
#pragma unroll
  for (int rep = 0; rep < 8; ++rep) {
    const int li = rep * 256 + t;
    const int k = li >> 5;
    const int d0 = (li & 31) * 4;
    const int g = g0 + k;
    const float* src;
    if (g < 8192)       src = V0 + ((size_t)kvh * 8192 + g) * 128 + d0;
    else if (g < 12288) src = V1 + ((size_t)kvh * 4096 + (g - 8192)) * 128 + d0;
    else                src = V2 + ((size_t)kvh * 2048 + (g - 12288)) * 128 + d0;
    const float4 v = ld4(src);
    h2 x = pk(v.x, v.y), y = pk(v.z, v.w);
    h4 q4; q4[0] = x[0]; q4[1] = x[1]; q4[2] = y[0]; q4[3] = y[1];
    *(h4*)((char*)T + k * 272 + d0 * 2) = q4;
  }
  __syncthreads();
#pragma unroll
  for (int rep = 0; rep < 4; ++rep) {
    const int li = rep * 256 + t;
    const int d = li >> 3;
    const int kc = (li & 7) * 8;
    h8 o;
#pragma unroll
    for (int j = 0; j < 8; ++j) o[j] = T[(kc + j) * 136 + d];
    *(h8*)(Vt + ((size_t)kvh * 128 + d) * 14336 + g0 + kc) = o;
  }
}

// ---------------- MFMA flash attention (split-K, qh-merged, wave-grouped) ----------------
// R7 exact: 128-key tiles, 8 waves (512 thr), group g=wv>>2 owns q-half g,
// wave wv&3 owns a 32-key slice. LDS 80 KB -> 2 blocks/CU -> 4 waves/SIMD. VGPR 64.
__global__ __launch_bounds__(512, 4) void attn_mfma_kernel(
    const float* __restrict__ q_ws,
    const float* __restrict__ cosT, const float* __restrict__ sinT,
    const float* __restrict__ K0, const float* __restrict__ K1, const float* __restrict__ K2,
    const float* __restrict__ V0, const float* __restrict__ V1, const float* __restrict__ V2,
    const int* __restrict__ loc,
    const f16* __restrict__ Vt, const int vt16,
    float* __restrict__ attn,
    float* __restrict__ Opart, float* __restrict__ Ml, const int NS)
{
  union ShmU {
    struct { f16 k[128 * 128]; f16 vt[128 * 128]; } t;
    struct { float o[2][32 * 132]; float m[8][32]; float l[8][32];
             float lg[2][32]; float mg[2][32]; } e;
  };
  __shared__ __align__(16) ShmU S;
  __shared__ __align__(16) f16 RQ[64 * 128];

  int unit, s, h, w, kvh;
  if (NS > 1) {
    const int C = 4 * NS;
    const int combo = blockIdx.x % C;
    const int idx = blockIdx.x / C;
    kvh = combo / NS; s = combo % NS;
    const int hh7 = idx % 7;
    w = idx / 7;
    h = kvh * 7 + hh7;
    unit = w * 28 + h;
  } else {
    unit = blockIdx.x; s = 0;
    h = unit % 28; w = unit / 28; kvh = h / 7;
  }

  const int tiles_per = 112 / NS;
  const int tile0 = s * tiles_per;
  const int tile1 = tile0 + tiles_per;

  const int t = threadIdx.x;
  const int lane = t & 63;
  const int wv = t >> 6;
  const int g  = wv >> 2;
  const int wg = wv & 3;
  const int wk = wg * 32;
  const int l31 = lane & 31;
  const int hh = lane >> 5;

  const size_t qb = (size_t)unit * 64 * 128;

  const float* K0b = K0 + (size_t)kvh * 8192 * 128;
  const float* K1b = K1 + (size_t)kvh * 4096 * 128;
  const float* K2b = K2 + (size_t)kvh * 2048 * 128;
  const float* V0b = V0 + (size_t)kvh * 8192 * 128;
  const float* V1b = V1 + (size_t)kvh * 4096 * 128;
  const float* V2b = V2 + (size_t)kvh * 2048 * 128;
  const f16* Vtg = Vt ? (Vt + (size_t)kvh * 128 * 14336) : (const f16*)nullptr;

  f32x16 acc[4];
#pragma unroll
  for (int i = 0; i < 4; ++i)
#pragma unroll
    for (int gg = 0; gg < 16; ++gg) acc[i][gg] = 0.f;

  h8 rq[8];
  float m_run = -INFINITY, l_run = 0.f;
  int locq = 0;
  int fprev = -1;

  for (int tile = tile0; tile < tile1; ++tile) {
    int f, rel; const float *Kg, *Vg;
    if (tile < 64)      { f = 0; rel = tile * 128;        Kg = K0b; Vg = V0b; }
    else if (tile < 96) { f = 1; rel = (tile - 64) * 128; Kg = K1b; Vg = V1b; }
    else                { f = 2; rel = (tile - 96) * 128; Kg = K2b; Vg = V2b; }
    const int gcat = tile * 128;
    const bool fsw = (f != fprev);
    fprev = f;

    if (fsw) {
      const size_t cb = ((size_t)(f * 2 + w)) * 64 * 128;
#pragma unroll
      for (int rep = 0; rep < 2; ++rep) {
        const int qr = rep * 32 + (t >> 4);
        const int d0 = (t & 15) * 8;
        const float* qp = q_ws + qb + (size_t)qr * 128;
        const float4 a0 = ld4(qp + d0), a1 = ld4(qp + d0 + 4);
        const int pd = (d0 < 64) ? d0 + 64 : d0 - 64;
        const float4 r0 = ld4(qp + pd), r1 = ld4(qp + pd + 4);
        const float sg = (d0 < 64) ? -1.f : 1.f;
        const float* cp = cosT + cb + (size_t)qr * 128;
        const float* sp = sinT + cb + (size_t)qr * 128;
        const float4 c0 = ld4(cp + d0), c1 = ld4(cp + d0 + 4);
        const float4 s0 = ld4(sp + d0), s1 = ld4(sp + d0 + 4);
        h8 hv = mk8(pk(a0.x * c0.x + sg * r0.x * s0.x, a0.y * c0.y + sg * r0.y * s0.y),
                    pk(a0.z * c0.z + sg * r0.z * s0.z, a0.w * c0.w + sg * r0.w * s0.w),
                    pk(a1.x * c1.x + sg * r1.x * s1.x, a1.y * c1.y + sg * r1.y * s1.y),
                    pk(a1.z * c1.z + sg * r1.z * s1.z, a1.w * c1.w + sg * r1.w * s1.w));
        *(h8*)((char*)RQ + qr * 256 + ((d0 * 2) ^ ((qr & 7) << 4))) = hv;
      }
      locq = loc[(f * 2 + w) * 64 + g * 32 + l31];
    }

    // ---- stage K (rows), V^T (d-rows) into LDS, XOR-swizzled 256B rows ----
    if (vt16) {
#pragma unroll
      for (int rep = 0; rep < 4; ++rep) {
        const int r = rep * 32 + (t >> 4);
        const int c0 = (t & 15) * 8;
        const float* kp = Kg + (size_t)(rel + r) * 128 + c0;
        const float4 a = ld4(kp), b = ld4(kp + 4);
        const h8 v = mk8(pk(a.x, a.y), pk(a.z, a.w), pk(b.x, b.y), pk(b.z, b.w));
        *(h8*)((char*)S.t.k + r * 256 + ((c0 * 2) ^ ((r & 7) << 4))) = v;
      }
#pragma unroll
      for (int rep = 0; rep < 4; ++rep) {
        const int d = rep * 32 + (t >> 4);
        const int kc = (t & 15) * 8;
        const h8 v = *(const h8*)(Vtg + (size_t)d * 14336 + gcat + kc);
        *(h8*)((char*)S.t.vt + d * 256 + ((kc * 2) ^ ((d & 7) << 4))) = v;
      }
    } else {
#pragma unroll
      for (int rep = 0; rep < 8; ++rep) {
        const int r = rep * 16 + (t >> 5);
        const int d0 = (t & 31) * 4;
        const float4 v = ld4(Kg + (size_t)(rel + r) * 128 + d0);
        h2 x = pk(v.x, v.y), y = pk(v.z, v.w);
        h4 q4; q4[0] = x[0]; q4[1] = x[1]; q4[2] = y[0]; q4[3] = y[1];
        *(h4*)((char*)S.t.k + r * 256 + ((d0 * 2) ^ ((r & 7) << 4))) = q4;
      }
#pragma unroll
      for (int rep = 0; rep < 8; ++rep) {
        const int d = t & 127;
        const int k0 = (rep * 4 + (t >> 7)) * 4;
        const float* vp = Vg + (size_t)(rel + k0) * 128 + d;
        const float b0 = vp[0], b1 = vp[128], b2 = vp[256], b3 = vp[384];
        h2 x = pk(b0, b1), y = pk(b2, b3);
        h4 q4; q4[0] = x[0]; q4[1] = x[1]; q4[2] = y[0]; q4[3] = y[1];
        *(h4*)((char*)S.t.vt + d * 256 + ((k0 * 2) ^ ((d & 7) << 4))) = q4;
      }
    }
    __syncthreads();

    if (fsw) {
#pragma unroll
      for (int c = 0; c < 8; ++c)
        rq[c] = *(const h8*)((const char*)RQ + (g * 32 + l31) * 256 +
                             (((c * 32) + hh * 16) ^ ((l31 & 7) << 4)));
    }

    // ---- QK^T (swapped) ----
    f32x16 sacc;
#pragma unroll
    for (int gg = 0; gg < 16; ++gg) sacc[gg] = 0.f;
    {
      const int r = wk + l31;
      const char* kb = (const char*)S.t.k + r * 256;
      const int sx = (r & 7) << 4;
      __builtin_amdgcn_s_setprio(1);
#pragma unroll
      for (int c = 0; c < 8; ++c) {
        const h8 a = *(const h8*)(kb + ((c * 32 + hh * 16) ^ sx));
        sacc = __builtin_amdgcn_mfma_f32_32x32x16_f16(a, rq[c], sacc, 0, 0, 0);
      }
      __builtin_amdgcn_s_setprio(0);
    }

    // ---- mask + scale + online softmax ----
    float p[16];
    float mt = -INFINITY;
#pragma unroll
    for (int gg = 0; gg < 16; ++gg) {
      const int kl = (gg & 3) + 8 * (gg >> 2) + 4 * hh;
      float z = sacc[gg] * SCALE;
      if (rel + wk + kl > locq) z = -INFINITY;
      p[gg] = z;
      mt = fmaxf(mt, z);
    }
    mt = fmaxf(mt, __shfl_xor(mt, 32, 64));
    if (!__all(mt <= m_run + 8.f)) {        // defer-max (T13)
      const float mn = fmaxf(m_run, mt);
      const float rr = __expf(m_run - mn);
      l_run *= rr;
#pragma unroll
      for (int i = 0; i < 4; ++i)
#pragma unroll
        for (int gg = 0; gg < 16; ++gg) acc[i][gg] *= rr;
      m_run = mn;
    }
    float ls = 0.f;
#pragma unroll
    for (int gg = 0; gg < 16; ++gg) { const float pe = __expf(p[gg] - m_run); p[gg] = pe; ls += pe; }
    l_run += ls + __shfl_xor(ls, 32, 64);

    // ---- P -> f16 B-fragments ----
    h2 wvv[8], xvv[8];
#pragma unroll
    for (int gg = 0; gg < 8; ++gg) wvv[gg] = pk(p[2 * gg], p[2 * gg + 1]);
#pragma unroll
    for (int gg = 0; gg < 8; ++gg) xvv[gg] = sw32(wvv[gg]);
    const h8 bp0 = hh ? mk8(xvv[2], xvv[3], wvv[2], wvv[3]) : mk8(wvv[0], wvv[1], xvv[0], xvv[1]);
    const h8 bp1 = hh ? mk8(xvv[6], xvv[7], wvv[6], wvv[7]) : mk8(wvv[4], wvv[5], xvv[4], xvv[5]);

    // ---- PV ----
    {
      const char* vb = (const char*)S.t.vt;
      __builtin_amdgcn_s_setprio(1);
#pragma unroll
      for (int dt = 0; dt < 4; ++dt) {
        const int d = dt * 32 + l31;
        const int sx = (d & 7) << 4;
        const char* vrow = vb + d * 256;
        const h8 a0 = *(const h8*)(vrow + ((2 * (wk + hh * 8)) ^ sx));
        const h8 a1 = *(const h8*)(vrow + ((2 * (wk + 16 + hh * 8)) ^ sx));
        acc[dt] = __builtin_amdgcn_mfma_f32_32x32x16_f16(a0, bp0, acc[dt], 0, 0, 0);
        acc[dt] = __builtin_amdgcn_mfma_f32_32x32x16_f16(a1, bp1, acc[dt], 0, 0, 0);
      }
      __builtin_amdgcn_s_setprio(0);
    }
    __syncthreads();
  }

  // ---- epilogue: per-group cross-wave combine ----
  if (lane < 32) { S.e.m[wv][l31] = m_run; S.e.l[wv][l31] = l_run; }
  {
    const float4 z4 = make_float4(0.f, 0.f, 0.f, 0.f);
    for (int i = t; i < 2 * 32 * 132 / 4; i += 512) ((float4*)S.e.o)[i] = z4;
  }
  __syncthreads();
  float M = -INFINITY;
#pragma unroll
  for (int j = 0; j < 4; ++j) M = fmaxf(M, S.e.m[g * 4 + j][l31]);
  float Lg = 0.f;
#pragma unroll
  for (int j = 0; j < 4; ++j) Lg += S.e.l[g * 4 + j][l31] * __expf(S.e.m[g * 4 + j][l31] - M);
  const float swf = __expf(m_run - M);
  if (wg == 0 && lane < 32) { S.e.lg[g][l31] = Lg; S.e.mg[g][l31] = M; }
  __syncthreads();

#pragma unroll
  for (int r = 0; r < 4; ++r) {
#pragma unroll
    for (int dt = 0; dt < 4; ++dt) {
#pragma unroll
      for (int gq = 0; gq < 4; ++gq) {
        if ((((dt * 2 + (gq >> 1)) - wg - r) & 3) == 0) {   // wave-uniform predicate
          const int db = dt * 32 + 8 * gq + 4 * hh;
          float4* pp = (float4*)&S.e.o[g][l31 * 132 + db];
          float4 v = *pp;
          v.x += acc[dt][gq * 4 + 0] * swf;
          v.y += acc[dt][gq * 4 + 1] * swf;
          v.z += acc[dt][gq * 4 + 2] * swf;
          v.w += acc[dt][gq * 4 + 3] * swf;
          *pp = v;
        }
      }
    }
    __syncthreads();
  }

  {
    const int q = t >> 3;
    const int hf = q >> 5;
    const int qr = q & 31;
    const int d0 = (t & 7) * 16;
    const float* op = &S.e.o[hf][qr * 132 + d0];
    if (NS == 1) {
      const float invl = 1.f / S.e.lg[hf][qr];
      float* dst = attn + ((size_t)(w * 64 + q)) * 3584 + h * 128 + d0;
#pragma unroll
      for (int i = 0; i < 4; ++i)
        st4(dst + 4 * i, make_float4(op[4*i] * invl, op[4*i+1] * invl, op[4*i+2] * invl, op[4*i+3] * invl));
    } else {
      float* dst = Opart + (((size_t)unit * NS + s) * 64 + q) * 128 + d0;
#pragma unroll
      for (int i = 0; i < 4; ++i)
        st4(dst + 4 * i, make_float4(op[4*i], op[4*i+1], op[4*i+2], op[4*i+3]));
      if (t < 64) {
        float* mlp = Ml + ((size_t)unit * NS + s) * 128;
        mlp[t] = S.e.mg[t >> 5][t & 31];
        mlp[64 + t] = S.e.lg[t >> 5][t & 31];
      }
    }
  }
}

// merge NS split partials. grid 56 x 512.
__global__ __launch_bounds__(512) void attn_combine_kernel(
    const float* __restrict__ Opart, const float* __restrict__ Ml,
    float* __restrict__ attn, const int NS)
{
  const int unit = blockIdx.x;
  const int h = unit % 28;
  const int w = unit / 28;
  const int t = threadIdx.x;
  const int q = t >> 3;
  const int d0 = (t & 7) * 16;

  float M = -INFINITY;
  for (int s = 0; s < NS; ++s) M = fmaxf(M, Ml[((size_t)unit * NS + s) * 128 + q]);
  float L = 0.f;
  float acc[16];
#pragma unroll
  for (int i = 0; i < 16; ++i) acc[i] = 0.f;
  for (int s = 0; s < NS; ++s) {
    const float ms = Ml[((size_t)unit * NS + s) * 128 + q];
    const float ls = Ml[((size_t)unit * NS + s) * 128 + 64 + q];
    const float wgt = __expf(ms - M);
    L += ls * wgt;
    const float* op = Opart + (((size_t)unit * NS + s) * 64 + q) * 128 + d0;
#pragma unroll
    for (int i = 0; i < 4; ++i) {
      const float4 v = ld4(op + 4 * i);
      acc[4 * i + 0] += v.x * wgt;
      acc[4 * i + 1] += v.y * wgt;
      acc[4 * i + 2] += v.z * wgt;
      acc[4 * i + 3] += v.w * wgt;
    }
  }
  const float invl = 1.f / L;
  float* dst = attn + ((size_t)(w * 64 + q)) * 3584 + h * 128 + d0;
#pragma unroll
  for (int i = 0; i < 4; ++i) {
    const float4 o = make_float4(acc[4 * i + 0] * invl, acc[4 * i + 1] * invl,
                                 acc[4 * i + 2] * invl, acc[4 * i + 3] * invl);
    st4(dst + 4 * i, o);
  }
}

extern "C" void kernel_launch(void* const* d_in, const int* in_sizes, int n_in,
                              void* d_out, int out_size, void* d_ws, size_t ws_size,
                              hipStream_t stream) {
  (void)n_in; (void)out_size;
  const float* hs = (const float*)d_in[0];
  const float* wq = (const float*)d_in[1];
  const float* bq = (const float*)d_in[2];
  const float* wo = (const float*)d_in[3];

  const float *K0, *V0, *K1, *V1, *K2, *V2, *cosT, *sinT;
  const int* loc;
  if (in_sizes[5] == in_sizes[4]) {  // dict order
    K0 = (const float*)d_in[4]; V0 = (const float*)d_in[5];
    K1 = (const float*)d_in[6]; V1 = (const float*)d_in[7];
    K2 = (const float*)d_in[8]; V2 = (const float*)d_in[9];
    loc = (const int*)d_in[10];
    cosT = (const float*)d_in[11]; sinT = (const float*)d_in[12];
  } else {                            // signature order
    K0 = (const float*)d_in[4]; K1 = (const float*)d_in[5]; K2 = (const float*)d_in[6];
    V0 = (const float*)d_in[7]; V1 = (const float*)d_in[8]; V2 = (const float*)d_in[9];
    cosT = (const float*)d_in[10]; sinT = (const float*)d_in[11];
    loc = (const int*)d_in[12];
  }

  float* outp = (float*)d_out;          // q [w][h][qn][d] between gemm1 and attn
  float* attn = (float*)d_ws;           // [128][3584] = 1,835,008 B
  char* base = (char*)d_ws;

  const size_t ATTN_B = (size_t)458752 * 4;            // 1,835,008
  const size_t RB = (size_t)4 * 128 * 14336 * 2;       // 14,680,064: Vt f16 / Gpart KS=8
  auto opartBytes = [](int ns){ return (size_t)56 * ns * 33280; };

  size_t off = ATTN_B;
  f16* Vt = nullptr; int vt16 = 0;
  float *Opart = nullptr, *Ml = nullptr, *Gpart = nullptr;
  int NS = 1, KS = 1;

  // Region R: Vt (attn phase) / Gpart (gemm phases) — lifetimes disjoint.
  const bool haveR = (ws_size >= off + RB + opartBytes(2));
  if (haveR) {
    Vt = (f16*)(base + off); vt16 = 1;
    Gpart = (float*)(base + off); KS = 8;           // 8 x 1.835 MB = RB exactly
    off += RB;
  }
  for (int cand = 8; cand >= 2; cand >>= 1) {
    if (ws_size >= off + opartBytes(cand)) {
      NS = cand;
      Opart = (float*)(base + off);
      Ml = Opart + (size_t)56 * cand * 64 * 128;
      off += opartBytes(cand);
      break;
    }
  }
  if (!haveR) {
    if (ws_size >= off + (size_t)8 * ATTN_B)      { KS = 8; Gpart = (float*)(base + off); }
    else if (ws_size >= off + (size_t)4 * ATTN_B) { KS = 4; Gpart = (float*)(base + off); }
  }

  // ---- gemm1: q = hs @ wq^T + bq, q-layout (grid x = 3584/64 = 56) ----
  if (KS > 1) {
    gemm_mfma_kernel<<<dim3(56, KS, 1), 256, 0, stream>>>(hs, wq, nullptr, nullptr, 1, Gpart, KS);
    gemm_reduce_kernel<<<448, 256, 0, stream>>>(Gpart, bq, outp, KS, 1);
  } else {
    gemm_mfma_kernel<<<dim3(56, 1, 1), 256, 0, stream>>>(hs, wq, bq, outp, 1, nullptr, 1);
  }

  if (vt16) vtrans_kernel<<<896, 256, 0, stream>>>(V0, V1, V2, Vt);   // after reduce1

  // ---- attention (qh-merged wave-grouped, split-K x NS, XCD-combo swizzle) ----
  const int grid = (NS > 1) ? 56 * NS : 56;
  attn_mfma_kernel<<<grid, 512, 0, stream>>>(
      outp, cosT, sinT, K0, K1, K2, V0, V1, V2, loc, Vt, vt16, attn, Opart, Ml, NS);
  if (NS > 1) attn_combine_kernel<<<56, 512, 0, stream>>>(Opart, Ml, attn, NS);

  // ---- gemm2: out = attn @ wo^T (Gpart overwrites Vt — Vt dead after attn) ----
  if (KS > 1) {
    gemm_mfma_kernel<<<dim3(56, KS, 1), 256, 0, stream>>>(attn, wo, nullptr, nullptr, 0, Gpart, KS);
    gemm_reduce_kernel<<<448, 256, 0, stream>>>(Gpart, nullptr, outp, KS, 0);
  } else {
    gemm_mfma_kernel<<<dim3(56, 1, 1), 256, 0, stream>>>(attn, wo, nullptr, outp, 0, nullptr, 1);
  }
}